// Round 14
// baseline (404.172 us; speedup 1.0000x reference)
//
#include <hip/hip_runtime.h>

#define BB 8
#define NN 8192
#define RR 2048
#define LL 4
#define TC 61
#define EPSF 1e-6f
#define BN (BB*NN)
#define OUTN (BN*3)

typedef unsigned short u16;
typedef unsigned int u32;
typedef _Float16 h2f __attribute__((ext_vector_type(2)));
typedef _Float16 h8 __attribute__((ext_vector_type(8)));
typedef float f4 __attribute__((ext_vector_type(4)));

__device__ __forceinline__ u32 packf16(float a, float b) {
  h2f h; h.x = (_Float16)a; h.y = (_Float16)b; return __builtin_bit_cast(u32, h);
}
__device__ __forceinline__ u16 f16b(float a) {
  _Float16 h = (_Float16)a; return __builtin_bit_cast(u16, h);
}
__device__ __forceinline__ float2 unpk(u32 a) {
  h2f h = __builtin_bit_cast(h2f, a); return make_float2((float)h.x, (float)h.y);
}
__device__ __forceinline__ float fdot2(u32 a, u32 b, float c) {
  return __builtin_amdgcn_fdot2(__builtin_bit_cast(h2f, a), __builtin_bit_cast(h2f, b), c, false);
}
__device__ __forceinline__ float frcp(float x) { return __builtin_amdgcn_rcpf(x); }
__device__ __forceinline__ float frsq(float x) { return __builtin_amdgcn_rsqf(x); }
__device__ __forceinline__ float fexp(float x) { return __expf(x); }
__device__ __forceinline__ int kmax_of(int n) {
  int aatom = n & 3, rres = n >> 2;
  return (aatom==0) ? (rres==0 ? 2 : 3)
       : (aatom==1) ? 3
       : (aatom==2) ? (rres==RR-1 ? 3 : 4) : 2;
}

__global__ __launch_bounds__(256) void k_const(float* out, float v) {
  int i = blockIdx.x*256 + threadIdx.x;
  if (i < OUTN) out[i] = v;
}

// ---------- weight pre-pack + te MLP + rhat (merged) ----------
struct WSrc { const float* m[11]; };
__global__ __launch_bounds__(256) void k_prep(WSrc s, u32* W16,
    const float* t, const float* w1, const float* b1,
    const float* w2, const float* b2, float* te2,
    const float* x, const int* nbr, u16* rhat) {
  if (blockIdx.x >= 1096) {               // rhat blocks
    int i = (blockIdx.x - 1096)*256 + threadIdx.x;   // BN*4 items
    int tok = i >> 2, k = i & 3;
    int b = tok >> 13, n = tok & (NN-1);
    int tj = b*NN + nbr[n*4 + k];
    float x0 = x[tok*3+0], x1 = x[tok*3+1], x2 = x[tok*3+2];
    float rx = x[tj*3+0] - x0, ry = x[tj*3+1] - x1, rz = x[tj*3+2] - x2;
    float ir = rsqrtf(rx*rx + ry*ry + rz*rz + EPSF);
    rhat[(size_t)(tok*4+k)*3 + 0] = f16b(rx * ir);
    rhat[(size_t)(tok*4+k)*3 + 1] = f16b(ry * ir);
    rhat[(size_t)(tok*4+k)*3 + 2] = f16b(rz * ir);
    return;
  }
  if (blockIdx.x >= 1088) {               // te blocks: one per batch
    __shared__ float s0[128], s1[128];
    int bb = blockIdx.x - 1088;
    int j = threadIdx.x;
    float tv = t[bb];
    if (j < 128) {
      int i = j & 63;
      float fr = expf(-9.210340371976184f * (float)i * (1.0f/64.0f));
      float em = tv * fr;
      s0[j] = (j < 64) ? sinf(em) : cosf(em);
    }
    __syncthreads();
    if (j < 128) {
      float acc = b1[j];
      for (int i2 = 0; i2 < 128; ++i2) acc += s0[i2] * w1[i2*128 + j];
      s1[j] = acc / (1.f + expf(-acc));
    }
    __syncthreads();
    if (j < TC) {
      float a2 = b2[j];
      for (int i2 = 0; i2 < 128; ++i2) a2 += s1[i2] * w2[i2*TC + j];
      te2[bb*TC + j] = a2;
    }
    return;
  }
  int i = blockIdx.x*256 + threadIdx.x;   // 278528 items
  if (i < 73728) {
    int m = i >> 13, rr = i & 8191, l = rr >> 11, r2 = rr & 2047;
    int c2 = r2 >> 6, col = r2 & 63;
    const float* src = s.m[m] + l*4096;
    W16[i] = packf16(src[(2*c2)*64 + col], src[(2*c2+1)*64 + col]);
  } else if (i < 106496) {
    int j2 = i - 73728; int l = j2 >> 13, r2 = j2 & 8191;
    int c2 = r2 >> 8, j = r2 & 255;
    const float* src = s.m[9] + l*16384;
    W16[i] = packf16(src[(2*c2)*256 + j], src[(2*c2+1)*256 + j]);
  } else if (i < 139264) {
    int j2 = i - 106496; int l = j2 >> 13, r2 = j2 & 8191;
    int jp = r2 >> 6, e = r2 & 63;
    const float* src = s.m[10] + l*16384;
    W16[i] = packf16(src[(2*jp)*64 + e], src[(2*jp+1)*64 + e]);
  } else if (i < 188416) {                // QKV B-frags
    int j2 = i - 139264;
    int l = j2 / 12288, rem = j2 % 12288;
    int m = rem >> 11, r2 = rem & 2047;
    int fb = r2 >> 8, li = r2 & 255;
    int nt = fb >> 1, kc = fb & 1;
    int lane = li >> 2, j = li & 3;
    int c2 = kc*16 + (lane>>4)*4 + j;
    int e  = nt*16 + (lane & 15);
    const float* src = s.m[m] + l*4096;
    W16[i] = packf16(src[(2*c2)*64 + e], src[(2*c2+1)*64 + e]);
  } else {                                // odfb B-frags
    int j2 = i - 188416;
    int l = j2 / 22528, rem = j2 % 22528;
    int li, fb, msel, N;
    const float* srcb;
    if (rem < 6144) {                     // Wo0 / Wo1 / Wff1 (64x64)
      msel = 6 + (rem >> 11);             // 6,7,8
      int r2 = rem & 2047;
      fb = r2 >> 8; li = r2 & 255;
      srcb = s.m[msel] + l*4096; N = 64;
      int nt = fb >> 1, kc = fb & 1;
      int lane = li >> 2, j = li & 3;
      int c2 = kc*16 + (lane>>4)*4 + j;
      int e  = nt*16 + (lane & 15);
      W16[i] = packf16(srcb[(2*c2)*N + e], srcb[(2*c2+1)*N + e]);
    } else if (rem < 14336) {             // ffa (64x256)
      int r2 = rem - 6144;
      fb = r2 >> 8; li = r2 & 255;
      srcb = s.m[9] + l*16384; N = 256;
      int nt = fb >> 1, kc = fb & 1;
      int lane = li >> 2, j = li & 3;
      int c2 = kc*16 + (lane>>4)*4 + j;
      int e  = nt*16 + (lane & 15);
      W16[i] = packf16(srcb[(2*c2)*N + e], srcb[(2*c2+1)*N + e]);
    } else {                              // ffb (256x64), fb = nt*8+kc
      int r2 = rem - 14336;
      fb = r2 >> 8; li = r2 & 255;
      srcb = s.m[10] + l*16384; N = 64;
      int nt = fb >> 3, kc = fb & 7;
      int lane = li >> 2, j = li & 3;
      int c2 = kc*16 + (lane>>4)*4 + j;
      int e  = nt*16 + (lane & 15);
      W16[i] = packf16(srcb[(2*c2)*N + e], srcb[(2*c2+1)*N + e]);
    }
  }
}

// ---------- fully fused per-layer kernel, v13 ----------
// = v12 (338us) with K1/V1 LDS slot TIME-SHARED: phase A stages K0,V0,K1
//   (logits + V0-accumulation), then V1 is projected into K1's slot (g1 frags
//   kept in regs) and V1 terms accumulated. LDS 53,248 -> 39,424 B
//   -> 4 blocks/CU (was 3). Barriers 3 -> 6 (measured near-free in v11).
#define QH  0
#define LQ1 1024
#define KVB 4096
#define LK0 (KVB)            // 1152
#define LV0 (KVB+1152)       // 1152
#define LK1 (KVB+2304)       // 3456 (phase A)
#define LV1 (KVB+2304)       // 3456 (phase B, same slot)
#define LO0q (KVB)           // O0: 1152 (overlays dead KV)
#define LO1q (KVB+1152)      // O1: 3456
#define FR0q 0               // res f0: 1024 (overlays dead Q)
#define FR1q 1024            // res f1: 3072
#define LDSU 9856            // 39,424 B -> 4 blocks/CU

__global__ __launch_bounds__(256, 4) void k_layer(const u32* __restrict__ W16, int l,
    const u32* __restrict__ f0i, const u32* __restrict__ f1i,
    const int* __restrict__ nbr, const u16* __restrict__ rhat,
    u32* __restrict__ f0o, u32* __restrict__ f1o,
    const float* __restrict__ wout, const float* __restrict__ bout,
    float* __restrict__ out,
    const float* __restrict__ x, const float* __restrict__ win1,
    const float* __restrict__ te2) {
  __shared__ __align__(16) u32 S[LDSU];
  int tid = threadIdx.x, wv = tid >> 6, lane = tid & 63;
  int arow = lane & 15, aq = lane >> 4;
  int ncol = arow, mb = aq*4;
  int t0g = blockIdx.x * 32;
  int b = t0g >> 13, n0 = t0g & (NN-1);
  const u32 ONE2 = 0x3C003C00u;

  // ---- P0: residual into regs (l==0: computed; else pre-issued loads) ----
  uint4 res0, res1a, res1b, res1c;
  if (l == 0) {
    {
      int t0 = tid >> 3, j0 = (tid & 7)*4;
      const float* x3 = x + ((size_t)b*NN + n0 + t0)*3;
      float xv[3] = {x3[0], x3[1], x3[2]};
      u32 tmp[4];
#pragma unroll
      for (int q = 0; q < 4; ++q) {
        int ca = 2*(j0+q), cb = ca+1;
        float va = (ca < TC) ? te2[b*TC+ca] : xv[ca-61];
        float vb = (cb < TC) ? te2[b*TC+cb] : xv[cb-61];
        tmp[q] = packf16(va, vb);
      }
      res0 = make_uint4(tmp[0], tmp[1], tmp[2], tmp[3]);
    }
    uint4* rr[3] = {&res1a, &res1b, &res1c};
#pragma unroll
    for (int k = 0; k < 3; ++k) {
      int idx = k*1024 + tid*4;
      int t = idx/96, rem = idx%96, v = rem >> 5, j = rem & 31;
      float xv = x[((size_t)b*NN + n0 + t)*3 + v];
      u32 tmp[4];
#pragma unroll
      for (int q = 0; q < 4; ++q)
        tmp[q] = packf16(xv*win1[2*(j+q)], xv*win1[2*(j+q)+1]);
      *rr[k] = make_uint4(tmp[0], tmp[1], tmp[2], tmp[3]);
    }
  } else {
    const u32* s0 = f0i + ((size_t)b*NN + n0)*32;   // 1024 u32 contiguous
    const u32* s1 = f1i + ((size_t)b*NN + n0)*96;   // 3072 u32 contiguous
    res0  = *(const uint4*)(s0 + tid*4);
    res1a = *(const uint4*)(s1 + (0*256 + tid)*4);
    res1b = *(const uint4*)(s1 + (1*256 + tid)*4);
    res1c = *(const uint4*)(s1 + (2*256 + tid)*4);
  }

  // ---- P2 helpers (function scope: projs reused in phase B) ----
  const u32* base = W16 + 139264 + l*12288;
  h8 g0f[2]; h8 g1f[3][2];

  auto ldraw = [&](int hr0, u32* r0, u32 (*r1)[8]) {
    int n = n0 - 2 + hr0 + arow;
    n = n < 0 ? 0 : (n > NN-1 ? NN-1 : n);
    size_t gt = (size_t)b*NN + n;
    if (l == 0) {
      const float* x3 = x + gt*3;
      float xv[3] = {x3[0], x3[1], x3[2]};
#pragma unroll
      for (int i = 0; i < 8; ++i) {
        int j = (i < 4) ? (aq*4+i) : (16 + aq*4 + (i-4));
        int ca = 2*j, cb = ca+1;
        float va = (ca < TC) ? te2[b*TC+ca] : xv[ca-61];
        float vb = (cb < TC) ? te2[b*TC+cb] : xv[cb-61];
        r0[i] = packf16(va, vb);
        float wa = win1[ca], wb = win1[cb];
#pragma unroll
        for (int v = 0; v < 3; ++v)
          r1[v][i] = packf16(xv[v]*wa, xv[v]*wb);
      }
    } else {
      *(uint4*)(r0)   = *(const uint4*)(f0i + gt*32 + aq*4);
      *(uint4*)(r0+4) = *(const uint4*)(f0i + gt*32 + 16 + aq*4);
#pragma unroll
      for (int v = 0; v < 3; ++v) {
        *(uint4*)(r1[v])   = *(const uint4*)(f1i + (gt*3+v)*32 + aq*4);
        *(uint4*)(r1[v]+4) = *(const uint4*)(f1i + (gt*3+v)*32 + 16 + aq*4);
      }
    }
  };

  auto mknorm = [&](const u32* r0, const u32 (*r1)[8]) {
    float s = 0.f, s2 = 0.f;
#pragma unroll
    for (int i = 0; i < 8; ++i) { s = fdot2(r0[i], ONE2, s); s2 = fdot2(r0[i], r0[i], s2); }
    s  += __shfl_xor(s, 16, 64);  s  += __shfl_xor(s, 32, 64);
    s2 += __shfl_xor(s2, 16, 64); s2 += __shfl_xor(s2, 32, 64);
    float mu = s*(1.f/64.f);
    float ri = frsq(fmaxf(s2*(1.f/64.f)-mu*mu, 0.f) + EPSF);
    _Float16 rih = (_Float16)ri, bih = (_Float16)(-mu*ri);
    h2f scv; scv.x = rih; scv.y = rih;
    h2f biv; biv.x = bih; biv.y = bih;
#pragma unroll
    for (int kc = 0; kc < 2; ++kc) {
      u32 t0[4];
#pragma unroll
      for (int i = 0; i < 4; ++i) {
        h2f g = __builtin_bit_cast(h2f, r0[kc*4+i]) * scv + biv;
        t0[i] = __builtin_bit_cast(u32, g);
      }
      g0f[kc] = __builtin_bit_cast(h8, make_uint4(t0[0], t0[1], t0[2], t0[3]));
    }
    float ss = 0.f;
#pragma unroll
    for (int v = 0; v < 3; ++v)
#pragma unroll
      for (int i = 0; i < 8; ++i) ss = fdot2(r1[v][i], r1[v][i], ss);
    ss += __shfl_xor(ss, 16, 64); ss += __shfl_xor(ss, 32, 64);
    float vs = frsq(ss*(1.f/64.f) + EPSF);
    _Float16 vsh = (_Float16)vs;
    h2f vsv; vsv.x = vsh; vsv.y = vsh;
#pragma unroll
    for (int v = 0; v < 3; ++v)
#pragma unroll
      for (int kc = 0; kc < 2; ++kc) {
        u32 t1[4];
#pragma unroll
        for (int i = 0; i < 4; ++i) {
          h2f g = __builtin_bit_cast(h2f, r1[v][kc*4+i]) * vsv;
          t1[i] = __builtin_bit_cast(u32, g);
        }
        g1f[v][kc] = __builtin_bit_cast(h8, make_uint4(t1[0], t1[1], t1[2], t1[3]));
      }
  };

  auto projs = [&](const h8* afr, const u32* wM, u16* outh, int ob, int rmax) {
#pragma unroll
    for (int nt = 0; nt < 4; ++nt) {
      f4 acc = {0.f, 0.f, 0.f, 0.f};
#pragma unroll
      for (int kc = 0; kc < 2; ++kc) {
        uint4 wb = *(const uint4*)(wM + (nt*2+kc)*256 + lane*4);
        acc = __builtin_amdgcn_mfma_f32_16x16x32_f16(afr[kc], __builtin_bit_cast(h8, wb), acc, 0, 0, 0);
      }
      int ex = ((nt ^ aq)&3)*16 + ncol;   // aq-XOR swizzle
#pragma unroll
      for (int r = 0; r < 4; ++r) {
        int orow = ob + mb + r;
        if (orow < rmax) outh[orow*64 + ex] = f16b(acc[r]);
      }
    }
  };

  // ---- P2a: norms + project Q (wave 3) / K0,V0,K1 (waves 0-2) ----
  {
    if (wv < 3) {
      int tb = wv*16;
      u32 r0[8]; u32 r1[3][8];
      ldraw(tb, r0, r1);
      mknorm(r0, r1);
      projs(g0f, base + 1*2048, (u16*)(S+LK0), tb, 36);
      projs(g0f, base + 2*2048, (u16*)(S+LV0), tb, 36);
#pragma unroll
      for (int v = 0; v < 3; ++v)
        projs(g1f[v], base + 4*2048, (u16*)(S+LK1) + v*2304, tb, 36);
      // g1f stays live for the V1 projection in phase B
    } else {
      u32 r0a[8], r1a[3][8], r0b[8], r1b[3][8];
      ldraw(2, r0a, r1a);        // both tiles' loads issue before any compute
      ldraw(18, r0b, r1b);
      mknorm(r0a, r1a);
      projs(g0f, base, (u16*)(S+QH), 0, 32);
#pragma unroll
      for (int v = 0; v < 3; ++v)
        projs(g1f[v], base + 3*2048, (u16*)(S+LQ1) + v*2048, 0, 32);
      mknorm(r0b, r1b);
      projs(g0f, base, (u16*)(S+QH), 16, 32);
#pragma unroll
      for (int v = 0; v < 3; ++v)
        projs(g1f[v], base + 3*2048, (u16*)(S+LQ1) + v*2048, 16, 32);
    }
  }
  __syncthreads();   // BAR 1: Q/K0/V0/K1 staged

  // ---- P3a: logits + softmax + V0-dependent accumulation ----
  u32 O0k[4], O1k[4][3], AWp[4][2];
  {
    const u32* Q0u = S + QH;
    const u32* Q1u = S + LQ1;
    const u32* K0u = S + LK0;
    const u32* V0u = S + LV0;
    const u32* K1u = S + LK1;
    int half = lane >> 5, l32 = lane & 31;
#pragma unroll
    for (int it = 0; it < 4; ++it) {
      int ct = wv*8 + it*2 + half;
      int n = n0 + ct;
      size_t gt = (size_t)b*NN + n;
      int km = kmax_of(n);
      int4 nb = *(const int4*)(nbr + n*4);
      int lr[4];
      {
        int xx;
        xx = nb.x - n0 + 2; lr[0] = xx < 0 ? 0 : (xx > 35 ? 35 : xx);
        xx = nb.y - n0 + 2; lr[1] = xx < 0 ? 0 : (xx > 35 ? 35 : xx);
        xx = nb.z - n0 + 2; lr[2] = xx < 0 ? 0 : (xx > 35 ? 35 : xx);
        xx = nb.w - n0 + 2; lr[3] = xx < 0 ? 0 : (xx > 35 ? 35 : xx);
      }
      int jq = l32 ^ (((ct>>2)&3)<<3);
      u32 q0p = Q0u[ct*32 + jq];
      u32 q1p[3];
#pragma unroll
      for (int v = 0; v < 3; ++v) q1p[v] = Q1u[v*1024 + ct*32 + jq];
      float p[4];
#pragma unroll
      for (int k = 0; k < 4; ++k) {
        int row = lr[k];
        int jk = l32 ^ (((row>>2)&3)<<3);
        float acc = fdot2(q0p, K0u[row*32 + jk], 0.f);
#pragma unroll
        for (int v = 0; v < 3; ++v)
          acc = fdot2(q1p[v], K1u[v*1152 + row*32 + jk], acc);
        p[k] = acc;
      }
#pragma unroll
      for (int m = 1; m < 8; m <<= 1) {
#pragma unroll
        for (int k = 0; k < 4; ++k) p[k] += __shfl_xor(p[k], m, 64);
      }
      float mx = -1e30f;
#pragma unroll
      for (int k = 0; k < 4; ++k) { p[k] *= 0.25f; if (k < km) mx = fmaxf(mx, p[k]); }
      float aw[4], ssum = 0.f;
#pragma unroll
      for (int k = 0; k < 4; ++k) { aw[k] = (k < km) ? fexp(p[k]-mx) : 0.f; ssum += aw[k]; }
      float inv = frcp(ssum);
      AWp[it][0] = packf16(aw[0]*inv, aw[1]*inv);
      AWp[it][1] = packf16(aw[2]*inv, aw[3]*inv);
      const uint2* rp = (const uint2*)(rhat + (size_t)gt*12);
      uint2 ra = rp[0], rb = rp[1], rc = rp[2];
      u32 rw[6] = {ra.x, ra.y, rb.x, rb.y, rc.x, rc.y};
      h2f o0p = {(_Float16)0.f, (_Float16)0.f};
      h2f o1p0 = o0p, o1p1 = o0p, o1p2 = o0p;
#pragma unroll
      for (int k = 0; k < 4; ++k) {
        int row = lr[k];
        int jk = l32 ^ (((row>>2)&3)<<3);
        float a = aw[k]*inv;
        _Float16 ah = (_Float16)a;
        h2f a2; a2.x = ah; a2.y = ah;
        h2f v0p = __builtin_bit_cast(h2f, V0u[row*32 + jk]);
#pragma unroll
        for (int v = 0; v < 3; ++v) {
          int idx = k*3 + v;
          u32 w = rw[idx>>1];
          u32 hh = (idx&1) ? (w >> 16) : (w & 0xffffu);
          h2f rh2 = __builtin_bit_cast(h2f, (hh << 16) | hh);
          h2f term = a2*(v0p*rh2);
          if (v == 0) o1p0 = term + o1p0;
          else if (v == 1) o1p1 = term + o1p1;
          else o1p2 = term + o1p2;
        }
        o0p = a2*v0p + o0p;
      }
      O0k[it] = __builtin_bit_cast(u32, o0p);
      O1k[it][0] = __builtin_bit_cast(u32, o1p0);
      O1k[it][1] = __builtin_bit_cast(u32, o1p1);
      O1k[it][2] = __builtin_bit_cast(u32, o1p2);
    }
  }
  __syncthreads();   // BAR 2: all K reads done -> K1 slot dead

  // ---- P2b: project V1 into K1's slot (g1f still in regs) ----
  if (wv < 3) {
    int tb = wv*16;
#pragma unroll
    for (int v = 0; v < 3; ++v)
      projs(g1f[v], base + 5*2048, (u16*)(S+LV1) + v*2304, tb, 36);
  }
  __syncthreads();   // BAR 3: V1 staged

  // ---- P3b: V1-dependent accumulation ----
  {
    const u32* V1u = S + LV1;
    int half = lane >> 5, l32 = lane & 31;
#pragma unroll
    for (int it = 0; it < 4; ++it) {
      int ct = wv*8 + it*2 + half;
      int n = n0 + ct;
      size_t gt = (size_t)b*NN + n;
      int4 nb = *(const int4*)(nbr + n*4);
      int lr[4];
      {
        int xx;
        xx = nb.x - n0 + 2; lr[0] = xx < 0 ? 0 : (xx > 35 ? 35 : xx);
        xx = nb.y - n0 + 2; lr[1] = xx < 0 ? 0 : (xx > 35 ? 35 : xx);
        xx = nb.z - n0 + 2; lr[2] = xx < 0 ? 0 : (xx > 35 ? 35 : xx);
        xx = nb.w - n0 + 2; lr[3] = xx < 0 ? 0 : (xx > 35 ? 35 : xx);
      }
      const uint2* rp = (const uint2*)(rhat + (size_t)gt*12);
      uint2 ra = rp[0], rb = rp[1], rc = rp[2];
      u32 rw[6] = {ra.x, ra.y, rb.x, rb.y, rc.x, rc.y};
      float2 awA = unpk(AWp[it][0]), awB = unpk(AWp[it][1]);
      float af4[4] = {awA.x, awA.y, awB.x, awB.y};
      h2f o0p = __builtin_bit_cast(h2f, O0k[it]);
      h2f o1p0 = __builtin_bit_cast(h2f, O1k[it][0]);
      h2f o1p1 = __builtin_bit_cast(h2f, O1k[it][1]);
      h2f o1p2 = __builtin_bit_cast(h2f, O1k[it][2]);
#pragma unroll
      for (int k = 0; k < 4; ++k) {
        int row = lr[k];
        int jk = l32 ^ (((row>>2)&3)<<3);
        _Float16 ah = (_Float16)af4[k];
        h2f a2; a2.x = ah; a2.y = ah;
        h2f v1p[3], rh2[3];
#pragma unroll
        for (int v = 0; v < 3; ++v) {
          v1p[v] = __builtin_bit_cast(h2f, V1u[v*1152 + row*32 + jk]);
          int idx = k*3 + v;
          u32 w = rw[idx>>1];
          u32 hh = (idx&1) ? (w >> 16) : (w & 0xffffu);
          rh2[v] = __builtin_bit_cast(h2f, (hh << 16) | hh);
        }
        h2f vd = v1p[0]*rh2[0];
        vd = v1p[1]*rh2[1] + vd;
        vd = v1p[2]*rh2[2] + vd;
        o0p  = a2*vd + o0p;
        o1p0 = a2*v1p[0] + o1p0;
        o1p1 = a2*v1p[1] + o1p1;
        o1p2 = a2*v1p[2] + o1p2;
      }
      O0k[it] = __builtin_bit_cast(u32, o0p);
      O1k[it][0] = __builtin_bit_cast(u32, o1p0);
      O1k[it][1] = __builtin_bit_cast(u32, o1p1);
      O1k[it][2] = __builtin_bit_cast(u32, o1p2);
    }
  }
  __syncthreads();   // BAR 4: V1 reads done -> KV region + Q region dead

  // ---- merged write phase: O into KV region, residuals into Q region ----
  {
    u32* o0u = S + LO0q;
    u32* o1u = S + LO1q;
    int half = lane >> 5, l32 = lane & 31;
#pragma unroll
    for (int it = 0; it < 4; ++it) {
      int ct = wv*8 + it*2 + half;
      o0u[ct*36 + l32] = O0k[it];
#pragma unroll
      for (int v = 0; v < 3; ++v)
        o1u[(v*32+ct)*36 + l32] = O1k[it][v];
    }
    uint4* d0 = (uint4*)(S + FR0q);
    d0[tid] = res0;
    uint4* d1 = (uint4*)(S + FR1q);
    d1[tid]       = res1a;
    d1[256 + tid] = res1b;
    d1[512 + tid] = res1c;
  }
  __syncthreads();   // BAR 5: O + residuals visible

  // ---- P4 prologue: a-frags from O -> regs ----
  int tl16 = (wv & 1)*16;
  h8 a1[3][2]; h8 a0[2];
  if (wv < 2) {
#pragma unroll
    for (int v = 0; v < 3; ++v)
#pragma unroll
      for (int kc = 0; kc < 2; ++kc)
        a1[v][kc] = __builtin_bit_cast(h8, *(const uint4*)(S + LO1q + (v*32 + tl16 + arow)*36 + kc*16 + aq*4));
  } else {
#pragma unroll
    for (int kc = 0; kc < 2; ++kc)
      a0[kc] = __builtin_bit_cast(h8, *(const uint4*)(S + LO0q + (tl16 + arow)*36 + kc*16 + aq*4));
  }
  __syncthreads();   // BAR 6: all a-frag reads done -> O region free for hp

  // ---- P4: out-proj + FF (waves 0-1: f1 path; waves 2-3: f0 path) ----
  {
    const u32* Wf = W16 + 188416 + l*22528;
    const u32* po0f = Wf;
    const u32* po1f = Wf + 2048;
    const u32* pf1f = Wf + 4096;
    const u32* paf  = Wf + 6144;
    const u32* pbf  = Wf + 14336;
    const u32* FR0 = S + FR0q;
    const u32* FR1 = S + FR1q;
    size_t gt0 = (size_t)b*NN + n0 + tl16;
    if (wv < 2) {
      // f1 path: Wo1 + residual -> vnorm -> ff1 + residual -> f1o (or score at l==3)
      float f1m[3][4][4];
#pragma unroll
      for (int v = 0; v < 3; ++v)
#pragma unroll
        for (int nt = 0; nt < 4; ++nt) {
          f4 acc = {0.f, 0.f, 0.f, 0.f};
#pragma unroll
          for (int kc = 0; kc < 2; ++kc) {
            uint4 wb = *(const uint4*)(po1f + (nt*2+kc)*256 + lane*4);
            acc = __builtin_amdgcn_mfma_f32_16x16x32_f16(a1[v][kc], __builtin_bit_cast(h8, wb), acc, 0, 0, 0);
          }
#pragma unroll
          for (int r = 0; r < 4; ++r) {
            int t = tl16 + mb + r;
            float2 pq = unpk(FR1[(t*3+v)*32 + nt*8 + (ncol>>1)]);
            f1m[v][nt][r] = acc[r] + ((ncol&1) ? pq.y : pq.x);
          }
        }
      float vs[4];
#pragma unroll
      for (int r = 0; r < 4; ++r) {
        float ss = 0.f;
#pragma unroll
        for (int v = 0; v < 3; ++v)
#pragma unroll
          for (int nt = 0; nt < 4; ++nt) ss += f1m[v][nt][r]*f1m[v][nt][r];
        ss += __shfl_xor(ss, 1, 64); ss += __shfl_xor(ss, 2, 64);
        ss += __shfl_xor(ss, 4, 64); ss += __shfl_xor(ss, 8, 64);
        vs[r] = frsq(ss*(1.f/64.f) + EPSF);
      }
      // vn overlays this wave's OWN FR1 region (residuals already consumed)
      u32* vn = S + FR1q + wv*1536;
      {
        u16* vnh = (u16*)vn;
#pragma unroll
        for (int v = 0; v < 3; ++v)
#pragma unroll
          for (int nt = 0; nt < 4; ++nt)
#pragma unroll
            for (int r = 0; r < 4; ++r)
              vnh[v*1024 + (mb+r)*64 + ((nt^aq)&3)*16 + ncol] = f16b(f1m[v][nt][r]*vs[r]);
      }
      float wl[3][4], sc[3][4];
      if (l == 3) {
#pragma unroll
        for (int v = 0; v < 3; ++v)
#pragma unroll
          for (int nt = 0; nt < 4; ++nt) { wl[v][nt] = wout[v*64 + nt*16 + ncol]; }
#pragma unroll
        for (int v = 0; v < 3; ++v)
#pragma unroll
          for (int r = 0; r < 4; ++r) sc[v][r] = 0.f;
      }
#pragma unroll
      for (int v = 0; v < 3; ++v)
#pragma unroll
        for (int nt = 0; nt < 4; ++nt) {
          f4 acc = {0.f, 0.f, 0.f, 0.f};
#pragma unroll
          for (int kc = 0; kc < 2; ++kc) {
            int lc = kc*2 + (aq>>1);
            int pc = (lc ^ (arow>>2)) & 3;
            h8 af = __builtin_bit_cast(h8, *(const uint4*)(vn + v*512 + arow*32 + pc*8 + (aq&1)*4));
            uint4 wb = *(const uint4*)(pf1f + (nt*2+kc)*256 + lane*4);
            acc = __builtin_amdgcn_mfma_f32_16x16x32_f16(af, __builtin_bit_cast(h8, wb), acc, 0, 0, 0);
          }
#pragma unroll
          for (int r = 0; r < 4; ++r) {
            size_t gt = gt0 + mb + r;
            float val = acc[r] + f1m[v][nt][r];
            if (l < 3) {
              float par = __shfl_xor(val, 1, 64);
              if (!(ncol & 1))
                f1o[(gt*3+v)*32 + nt*8 + (ncol>>1)] = packf16(val, par);
            } else {
              sc[v][r] += val * wl[v][nt];
            }
          }
        }
      if (l == 3) {
#pragma unroll
        for (int v = 0; v < 3; ++v)
#pragma unroll
          for (int r = 0; r < 4; ++r) {
            float xx = sc[v][r];
            xx += __shfl_xor(xx, 1, 64); xx += __shfl_xor(xx, 2, 64);
            xx += __shfl_xor(xx, 4, 64); xx += __shfl_xor(xx, 8, 64);
            if (ncol == 0) out[(gt0 + mb + r)*3 + v] = xx + bout[v];
          }
      }
    } else if (l < 3) {
      // f0 path: Wo0 + residual -> LN -> ffa/silu -> ffb + residual -> f0o
      float f0m[4][4];
#pragma unroll
      for (int nt = 0; nt < 4; ++nt) {
        f4 acc = {0.f, 0.f, 0.f, 0.f};
#pragma unroll
        for (int kc = 0; kc < 2; ++kc) {
          uint4 wb = *(const uint4*)(po0f + (nt*2+kc)*256 + lane*4);
          acc = __builtin_amdgcn_mfma_f32_16x16x32_f16(a0[kc], __builtin_bit_cast(h8, wb), acc, 0, 0, 0);
        }
#pragma unroll
        for (int r = 0; r < 4; ++r) {
          int t = tl16 + mb + r;
          float2 pq = unpk(FR0[t*32 + nt*8 + (ncol>>1)]);
          f0m[nt][r] = acc[r] + ((ncol&1) ? pq.y : pq.x);
        }
      }
      float mu[4], ri[4];
#pragma unroll
      for (int r = 0; r < 4; ++r) {
        float sg = 0.f, s2 = 0.f;
#pragma unroll
        for (int nt = 0; nt < 4; ++nt) { sg += f0m[nt][r]; s2 += f0m[nt][r]*f0m[nt][r]; }
        sg += __shfl_xor(sg, 1, 64); sg += __shfl_xor(sg, 2, 64);
        sg += __shfl_xor(sg, 4, 64); sg += __shfl_xor(sg, 8, 64);
        s2 += __shfl_xor(s2, 1, 64); s2 += __shfl_xor(s2, 2, 64);
        s2 += __shfl_xor(s2, 4, 64); s2 += __shfl_xor(s2, 8, 64);
        mu[r] = sg*(1.f/64.f);
        ri[r] = frsq(fmaxf(s2*(1.f/64.f)-mu[r]*mu[r], 0.f) + EPSF);
      }
      // gg overlays this wave's OWN FR0 region
      u32* gg = S + FR0q + (wv & 1)*512;
      {
        u16* gh = (u16*)gg;
#pragma unroll
        for (int nt = 0; nt < 4; ++nt)
#pragma unroll
          for (int r = 0; r < 4; ++r)
            gh[(mb+r)*64 + ((nt^aq)&3)*16 + ncol] = f16b((f0m[nt][r]-mu[r])*ri[r]);
      }
      // hp: 16 rows x 256 halves (128 u32), chunk-XOR swizzled; overlays dead O region
      u32* hp = S + KVB + (wv-2)*2048;
      {
        h8 ga[2];
#pragma unroll
        for (int kc = 0; kc < 2; ++kc) {
          int lc = kc*2 + (aq>>1);
          int pc = (lc ^ (arow>>2)) & 3;
          ga[kc] = __builtin_bit_cast(h8, *(const uint4*)(gg + arow*32 + pc*8 + (aq&1)*4));
        }
        u16* hhh = (u16*)hp;
#pragma unroll
        for (int nt16 = 0; nt16 < 16; ++nt16) {
          f4 acc = {0.f, 0.f, 0.f, 0.f};
#pragma unroll
          for (int kc = 0; kc < 2; ++kc) {
            uint4 wb = *(const uint4*)(paf + (nt16*2+kc)*256 + lane*4);
            acc = __builtin_amdgcn_mfma_f32_16x16x32_f16(ga[kc], __builtin_bit_cast(h8, wb), acc, 0, 0, 0);
          }
#pragma unroll
          for (int r = 0; r < 4; ++r) {
            float a = acc[r];
            int row = mb + r;
            int chunk = (nt16*2 + (ncol>>3)) ^ (row & 7);
            hhh[row*256 + chunk*8 + (ncol&7)] = f16b(a * frcp(1.f + fexp(-a)));
          }
        }
      }
#pragma unroll
      for (int nt = 0; nt < 4; ++nt) {
        f4 acc = {0.f, 0.f, 0.f, 0.f};
#pragma unroll
        for (int kc = 0; kc < 8; ++kc) {
          int c = kc*4 + aq;
          h8 af = __builtin_bit_cast(h8, *(const uint4*)(hp + arow*128 + ((c ^ (arow & 7))<<2)));
          uint4 wb = *(const uint4*)(pbf + (nt*8+kc)*256 + lane*4);
          acc = __builtin_amdgcn_mfma_f32_16x16x32_f16(af, __builtin_bit_cast(h8, wb), acc, 0, 0, 0);
        }
#pragma unroll
        for (int r = 0; r < 4; ++r) {
          size_t gt = gt0 + mb + r;
          float val = acc[r] + f0m[nt][r];
          float par = __shfl_xor(val, 1, 64);
          if (!(ncol & 1))
            f0o[gt*32 + nt*8 + (ncol>>1)] = packf16(val, par);
        }
      }
    }
  }
}

extern "C" void kernel_launch(void* const* d_in, const int* in_sizes, int n_in,
                              void* d_out, int out_size, void* d_ws, size_t ws_size,
                              hipStream_t stream) {
  float* out = (float*)d_out;
  static const int exp23[23] = {196608,196608,8,32768,32768,16384,128,7808,61,64,
                                16384,16384,16384,16384,16384,16384,16384,16384,
                                65536,65536,16384,192,3};
  bool ok23 = (n_in == 23), ok22 = (n_in == 22);
  int bad = -1;
  if (ok23) {
    for (int i = 0; i < 23; ++i) if (in_sizes[i] != exp23[i]) { ok23 = false; bad = i; break; }
  }
  if (!ok23 && ok22) {
    for (int i = 0; i < 22; ++i) {
      int want = (i == 0) ? exp23[0] : exp23[i+1];
      if (in_sizes[i] != want) { ok22 = false; if (bad < 0) bad = i; break; }
    }
  } else ok22 = false;
  if (!ok23 && !ok22) {
    k_const<<<768, 256, 0, stream>>>(out, (float)(3000 + (bad < 0 ? 100 + n_in : bad)));
    return;
  }
  int sh = ok23 ? 0 : -1;
  const int* nbr = (const int*)d_in[3 + sh];
  const float* F[20];
  F[0] = (const float*)d_in[0];
  F[1] = (const float*)d_in[2 + sh];
  for (int j = 0; j < 18; ++j) F[2 + j] = (const float*)d_in[5 + sh + j];

  char* ws = (char*)d_ws;
  u32*   W16  = (u32*)ws;                           // 1,114,112 B
  float* te2  = (float*)(ws + 1114112);             // 2,048 B
  u16*   rhat = (u16*)(ws + 1116160);               // 1,572,864 B
  u32*   f0A  = (u32*)(ws + 2689024);               // 8,388,608 B
  u32*   f1A  = (u32*)(ws + 11077632);              // 25,165,824 B
  u32*   f0B  = (u32*)(ws + 36243456);              // 8,388,608 B
  u32*   f1B  = (u32*)(ws + 44632064);              // 25,165,824 B -> end 69,797,888

  WSrc s;
  s.m[0]=F[7]; s.m[1]=F[8]; s.m[2]=F[9]; s.m[3]=F[10]; s.m[4]=F[11]; s.m[5]=F[12];
  s.m[6]=F[13]; s.m[7]=F[14]; s.m[8]=F[17]; s.m[9]=F[15]; s.m[10]=F[16];

  k_prep<<<1096 + BN*4/256, 256, 0, stream>>>(s, W16, F[1], F[2], F[3], F[4], F[5], te2,
                                              F[0], nbr, rhat);
  for (int l = 0; l < LL; ++l) {
    const u32* fi0 = (l & 1) ? f0B : f0A;
    const u32* fi1 = (l & 1) ? f1B : f1A;
    u32*       fo0 = (l & 1) ? f0A : f0B;
    u32*       fo1 = (l & 1) ? f1A : f1B;
    k_layer<<<BN/32, 256, 0, stream>>>(W16, l, fi0, fi1, nbr, rhat, fo0, fo1,
                                       F[18], F[19], out, F[0], F[6], te2);
  }
}

// Round 15
// 360.951 us; speedup vs baseline: 1.1197x; 1.1197x over previous
//
#include <hip/hip_runtime.h>

#define BB 8
#define NN 8192
#define RR 2048
#define LL 4
#define TC 61
#define EPSF 1e-6f
#define BN (BB*NN)
#define OUTN (BN*3)

typedef unsigned short u16;
typedef unsigned int u32;
typedef _Float16 h2f __attribute__((ext_vector_type(2)));
typedef _Float16 h8 __attribute__((ext_vector_type(8)));
typedef float f4 __attribute__((ext_vector_type(4)));

__device__ __forceinline__ u32 packf16(float a, float b) {
  h2f h; h.x = (_Float16)a; h.y = (_Float16)b; return __builtin_bit_cast(u32, h);
}
__device__ __forceinline__ u16 f16b(float a) {
  _Float16 h = (_Float16)a; return __builtin_bit_cast(u16, h);
}
__device__ __forceinline__ float2 unpk(u32 a) {
  h2f h = __builtin_bit_cast(h2f, a); return make_float2((float)h.x, (float)h.y);
}
__device__ __forceinline__ float fdot2(u32 a, u32 b, float c) {
  return __builtin_amdgcn_fdot2(__builtin_bit_cast(h2f, a), __builtin_bit_cast(h2f, b), c, false);
}
__device__ __forceinline__ float frcp(float x) { return __builtin_amdgcn_rcpf(x); }
__device__ __forceinline__ float frsq(float x) { return __builtin_amdgcn_rsqf(x); }
__device__ __forceinline__ float fexp(float x) { return __expf(x); }
__device__ __forceinline__ int kmax_of(int n) {
  int aatom = n & 3, rres = n >> 2;
  return (aatom==0) ? (rres==0 ? 2 : 3)
       : (aatom==1) ? 3
       : (aatom==2) ? (rres==RR-1 ? 3 : 4) : 2;
}

__global__ __launch_bounds__(256) void k_const(float* out, float v) {
  int i = blockIdx.x*256 + threadIdx.x;
  if (i < OUTN) out[i] = v;
}

// ---------- weight pre-pack + te MLP + rhat (merged) ----------
struct WSrc { const float* m[11]; };
__global__ __launch_bounds__(256) void k_prep(WSrc s, u32* W16,
    const float* t, const float* w1, const float* b1,
    const float* w2, const float* b2, float* te2,
    const float* x, const int* nbr, u16* rhat) {
  if (blockIdx.x >= 1096) {               // rhat blocks
    int i = (blockIdx.x - 1096)*256 + threadIdx.x;   // BN*4 items
    int tok = i >> 2, k = i & 3;
    int b = tok >> 13, n = tok & (NN-1);
    int tj = b*NN + nbr[n*4 + k];
    float x0 = x[tok*3+0], x1 = x[tok*3+1], x2 = x[tok*3+2];
    float rx = x[tj*3+0] - x0, ry = x[tj*3+1] - x1, rz = x[tj*3+2] - x2;
    float ir = rsqrtf(rx*rx + ry*ry + rz*rz + EPSF);
    rhat[(size_t)(tok*4+k)*3 + 0] = f16b(rx * ir);
    rhat[(size_t)(tok*4+k)*3 + 1] = f16b(ry * ir);
    rhat[(size_t)(tok*4+k)*3 + 2] = f16b(rz * ir);
    return;
  }
  if (blockIdx.x >= 1088) {               // te blocks: one per batch
    __shared__ float s0[128], s1[128];
    int bb = blockIdx.x - 1088;
    int j = threadIdx.x;
    float tv = t[bb];
    if (j < 128) {
      int i = j & 63;
      float fr = expf(-9.210340371976184f * (float)i * (1.0f/64.0f));
      float em = tv * fr;
      s0[j] = (j < 64) ? sinf(em) : cosf(em);
    }
    __syncthreads();
    if (j < 128) {
      float acc = b1[j];
      for (int i2 = 0; i2 < 128; ++i2) acc += s0[i2] * w1[i2*128 + j];
      s1[j] = acc / (1.f + expf(-acc));
    }
    __syncthreads();
    if (j < TC) {
      float a2 = b2[j];
      for (int i2 = 0; i2 < 128; ++i2) a2 += s1[i2] * w2[i2*TC + j];
      te2[bb*TC + j] = a2;
    }
    return;
  }
  int i = blockIdx.x*256 + threadIdx.x;   // 278528 items
  if (i < 73728) {
    int m = i >> 13, rr = i & 8191, l = rr >> 11, r2 = rr & 2047;
    int c2 = r2 >> 6, col = r2 & 63;
    const float* src = s.m[m] + l*4096;
    W16[i] = packf16(src[(2*c2)*64 + col], src[(2*c2+1)*64 + col]);
  } else if (i < 106496) {
    int j2 = i - 73728; int l = j2 >> 13, r2 = j2 & 8191;
    int c2 = r2 >> 8, j = r2 & 255;
    const float* src = s.m[9] + l*16384;
    W16[i] = packf16(src[(2*c2)*256 + j], src[(2*c2+1)*256 + j]);
  } else if (i < 139264) {
    int j2 = i - 106496; int l = j2 >> 13, r2 = j2 & 8191;
    int jp = r2 >> 6, e = r2 & 63;
    const float* src = s.m[10] + l*16384;
    W16[i] = packf16(src[(2*jp)*64 + e], src[(2*jp+1)*64 + e]);
  } else if (i < 188416) {                // QKV B-frags
    int j2 = i - 139264;
    int l = j2 / 12288, rem = j2 % 12288;
    int m = rem >> 11, r2 = rem & 2047;
    int fb = r2 >> 8, li = r2 & 255;
    int nt = fb >> 1, kc = fb & 1;
    int lane = li >> 2, j = li & 3;
    int c2 = kc*16 + (lane>>4)*4 + j;
    int e  = nt*16 + (lane & 15);
    const float* src = s.m[m] + l*4096;
    W16[i] = packf16(src[(2*c2)*64 + e], src[(2*c2+1)*64 + e]);
  } else {                                // odfb B-frags
    int j2 = i - 188416;
    int l = j2 / 22528, rem = j2 % 22528;
    int li, fb, msel, N;
    const float* srcb;
    if (rem < 6144) {                     // Wo0 / Wo1 / Wff1 (64x64)
      msel = 6 + (rem >> 11);             // 6,7,8
      int r2 = rem & 2047;
      fb = r2 >> 8; li = r2 & 255;
      srcb = s.m[msel] + l*4096; N = 64;
      int nt = fb >> 1, kc = fb & 1;
      int lane = li >> 2, j = li & 3;
      int c2 = kc*16 + (lane>>4)*4 + j;
      int e  = nt*16 + (lane & 15);
      W16[i] = packf16(srcb[(2*c2)*N + e], srcb[(2*c2+1)*N + e]);
    } else if (rem < 14336) {             // ffa (64x256)
      int r2 = rem - 6144;
      fb = r2 >> 8; li = r2 & 255;
      srcb = s.m[9] + l*16384; N = 256;
      int nt = fb >> 1, kc = fb & 1;
      int lane = li >> 2, j = li & 3;
      int c2 = kc*16 + (lane>>4)*4 + j;
      int e  = nt*16 + (lane & 15);
      W16[i] = packf16(srcb[(2*c2)*N + e], srcb[(2*c2+1)*N + e]);
    } else {                              // ffb (256x64), fb = nt*8+kc
      int r2 = rem - 14336;
      fb = r2 >> 8; li = r2 & 255;
      srcb = s.m[10] + l*16384; N = 64;
      int nt = fb >> 3, kc = fb & 7;
      int lane = li >> 2, j = li & 3;
      int c2 = kc*16 + (lane>>4)*4 + j;
      int e  = nt*16 + (lane & 15);
      W16[i] = packf16(srcb[(2*c2)*N + e], srcb[(2*c2+1)*N + e]);
    }
  }
}

// ---------- fully fused per-layer kernel, v14 ----------
// = v13 (4 blocks/CU structure) minus the two register hogs that spilled:
//   (a) wave 3 does its two Q tiles SEQUENTIALLY (peak -32 VGPR),
//   (b) residuals loaded/computed in the merged-write phase, not pre-held
//       (-16 VGPR held). LDS 39,424 B -> 4 blocks/CU.
#define QH  0
#define LQ1 1024
#define KVB 4096
#define LK0 (KVB)            // 1152
#define LV0 (KVB+1152)       // 1152
#define LK1 (KVB+2304)       // 3456 (phase A)
#define LV1 (KVB+2304)       // 3456 (phase B, same slot)
#define LO0q (KVB)           // O0: 1152 (overlays dead KV)
#define LO1q (KVB+1152)      // O1: 3456
#define FR0q 0               // res f0: 1024 (overlays dead Q)
#define FR1q 1024            // res f1: 3072
#define LDSU 9856            // 39,424 B -> 4 blocks/CU

__global__ __launch_bounds__(256, 4) void k_layer(const u32* __restrict__ W16, int l,
    const u32* __restrict__ f0i, const u32* __restrict__ f1i,
    const int* __restrict__ nbr, const u16* __restrict__ rhat,
    u32* __restrict__ f0o, u32* __restrict__ f1o,
    const float* __restrict__ wout, const float* __restrict__ bout,
    float* __restrict__ out,
    const float* __restrict__ x, const float* __restrict__ win1,
    const float* __restrict__ te2) {
  __shared__ __align__(16) u32 S[LDSU];
  int tid = threadIdx.x, wv = tid >> 6, lane = tid & 63;
  int arow = lane & 15, aq = lane >> 4;
  int ncol = arow, mb = aq*4;
  int t0g = blockIdx.x * 32;
  int b = t0g >> 13, n0 = t0g & (NN-1);
  const u32 ONE2 = 0x3C003C00u;

  // ---- P2 helpers ----
  const u32* base = W16 + 139264 + l*12288;
  h8 g0f[2]; h8 g1f[3][2];

  auto ldraw = [&](int hr0, u32* r0, u32 (*r1)[8]) {
    int n = n0 - 2 + hr0 + arow;
    n = n < 0 ? 0 : (n > NN-1 ? NN-1 : n);
    size_t gt = (size_t)b*NN + n;
    if (l == 0) {
      const float* x3 = x + gt*3;
      float xv[3] = {x3[0], x3[1], x3[2]};
#pragma unroll
      for (int i = 0; i < 8; ++i) {
        int j = (i < 4) ? (aq*4+i) : (16 + aq*4 + (i-4));
        int ca = 2*j, cb = ca+1;
        float va = (ca < TC) ? te2[b*TC+ca] : xv[ca-61];
        float vb = (cb < TC) ? te2[b*TC+cb] : xv[cb-61];
        r0[i] = packf16(va, vb);
        float wa = win1[ca], wb = win1[cb];
#pragma unroll
        for (int v = 0; v < 3; ++v)
          r1[v][i] = packf16(xv[v]*wa, xv[v]*wb);
      }
    } else {
      *(uint4*)(r0)   = *(const uint4*)(f0i + gt*32 + aq*4);
      *(uint4*)(r0+4) = *(const uint4*)(f0i + gt*32 + 16 + aq*4);
#pragma unroll
      for (int v = 0; v < 3; ++v) {
        *(uint4*)(r1[v])   = *(const uint4*)(f1i + (gt*3+v)*32 + aq*4);
        *(uint4*)(r1[v]+4) = *(const uint4*)(f1i + (gt*3+v)*32 + 16 + aq*4);
      }
    }
  };

  auto mknorm = [&](const u32* r0, const u32 (*r1)[8]) {
    float s = 0.f, s2 = 0.f;
#pragma unroll
    for (int i = 0; i < 8; ++i) { s = fdot2(r0[i], ONE2, s); s2 = fdot2(r0[i], r0[i], s2); }
    s  += __shfl_xor(s, 16, 64);  s  += __shfl_xor(s, 32, 64);
    s2 += __shfl_xor(s2, 16, 64); s2 += __shfl_xor(s2, 32, 64);
    float mu = s*(1.f/64.f);
    float ri = frsq(fmaxf(s2*(1.f/64.f)-mu*mu, 0.f) + EPSF);
    _Float16 rih = (_Float16)ri, bih = (_Float16)(-mu*ri);
    h2f scv; scv.x = rih; scv.y = rih;
    h2f biv; biv.x = bih; biv.y = bih;
#pragma unroll
    for (int kc = 0; kc < 2; ++kc) {
      u32 t0[4];
#pragma unroll
      for (int i = 0; i < 4; ++i) {
        h2f g = __builtin_bit_cast(h2f, r0[kc*4+i]) * scv + biv;
        t0[i] = __builtin_bit_cast(u32, g);
      }
      g0f[kc] = __builtin_bit_cast(h8, make_uint4(t0[0], t0[1], t0[2], t0[3]));
    }
    float ss = 0.f;
#pragma unroll
    for (int v = 0; v < 3; ++v)
#pragma unroll
      for (int i = 0; i < 8; ++i) ss = fdot2(r1[v][i], r1[v][i], ss);
    ss += __shfl_xor(ss, 16, 64); ss += __shfl_xor(ss, 32, 64);
    float vs = frsq(ss*(1.f/64.f) + EPSF);
    _Float16 vsh = (_Float16)vs;
    h2f vsv; vsv.x = vsh; vsv.y = vsh;
#pragma unroll
    for (int v = 0; v < 3; ++v)
#pragma unroll
      for (int kc = 0; kc < 2; ++kc) {
        u32 t1[4];
#pragma unroll
        for (int i = 0; i < 4; ++i) {
          h2f g = __builtin_bit_cast(h2f, r1[v][kc*4+i]) * vsv;
          t1[i] = __builtin_bit_cast(u32, g);
        }
        g1f[v][kc] = __builtin_bit_cast(h8, make_uint4(t1[0], t1[1], t1[2], t1[3]));
      }
  };

  auto projs = [&](const h8* afr, const u32* wM, u16* outh, int ob, int rmax) {
#pragma unroll
    for (int nt = 0; nt < 4; ++nt) {
      f4 acc = {0.f, 0.f, 0.f, 0.f};
#pragma unroll
      for (int kc = 0; kc < 2; ++kc) {
        uint4 wb = *(const uint4*)(wM + (nt*2+kc)*256 + lane*4);
        acc = __builtin_amdgcn_mfma_f32_16x16x32_f16(afr[kc], __builtin_bit_cast(h8, wb), acc, 0, 0, 0);
      }
      int ex = ((nt ^ aq)&3)*16 + ncol;   // aq-XOR swizzle
#pragma unroll
      for (int r = 0; r < 4; ++r) {
        int orow = ob + mb + r;
        if (orow < rmax) outh[orow*64 + ex] = f16b(acc[r]);
      }
    }
  };

  // ---- P2a: norms + project Q (wave 3, sequential tiles) / K0,V0,K1 (waves 0-2) ----
  {
    if (wv < 3) {
      int tb = wv*16;
      u32 r0[8]; u32 r1[3][8];
      ldraw(tb, r0, r1);
      mknorm(r0, r1);
      projs(g0f, base + 1*2048, (u16*)(S+LK0), tb, 36);
      projs(g0f, base + 2*2048, (u16*)(S+LV0), tb, 36);
#pragma unroll
      for (int v = 0; v < 3; ++v)
        projs(g1f[v], base + 4*2048, (u16*)(S+LK1) + v*2304, tb, 36);
      // g1f stays live for the V1 projection in phase B
    } else {
#pragma unroll
      for (int qt = 0; qt < 2; ++qt) {
        u32 r0[8]; u32 r1[3][8];
        ldraw(2 + qt*16, r0, r1);
        mknorm(r0, r1);
        projs(g0f, base, (u16*)(S+QH), qt*16, 32);
#pragma unroll
        for (int v = 0; v < 3; ++v)
          projs(g1f[v], base + 3*2048, (u16*)(S+LQ1) + v*2048, qt*16, 32);
      }
    }
  }
  __syncthreads();   // BAR 1: Q/K0/V0/K1 staged

  // ---- P3a: logits + softmax + V0-dependent accumulation ----
  u32 O0k[4], O1k[4][3], AWp[4][2];
  {
    const u32* Q0u = S + QH;
    const u32* Q1u = S + LQ1;
    const u32* K0u = S + LK0;
    const u32* V0u = S + LV0;
    const u32* K1u = S + LK1;
    int half = lane >> 5, l32 = lane & 31;
#pragma unroll
    for (int it = 0; it < 4; ++it) {
      int ct = wv*8 + it*2 + half;
      int n = n0 + ct;
      size_t gt = (size_t)b*NN + n;
      int km = kmax_of(n);
      int4 nb = *(const int4*)(nbr + n*4);
      int lr[4];
      {
        int xx;
        xx = nb.x - n0 + 2; lr[0] = xx < 0 ? 0 : (xx > 35 ? 35 : xx);
        xx = nb.y - n0 + 2; lr[1] = xx < 0 ? 0 : (xx > 35 ? 35 : xx);
        xx = nb.z - n0 + 2; lr[2] = xx < 0 ? 0 : (xx > 35 ? 35 : xx);
        xx = nb.w - n0 + 2; lr[3] = xx < 0 ? 0 : (xx > 35 ? 35 : xx);
      }
      int jq = l32 ^ (((ct>>2)&3)<<3);
      u32 q0p = Q0u[ct*32 + jq];
      u32 q1p[3];
#pragma unroll
      for (int v = 0; v < 3; ++v) q1p[v] = Q1u[v*1024 + ct*32 + jq];
      float p[4];
#pragma unroll
      for (int k = 0; k < 4; ++k) {
        int row = lr[k];
        int jk = l32 ^ (((row>>2)&3)<<3);
        float acc = fdot2(q0p, K0u[row*32 + jk], 0.f);
#pragma unroll
        for (int v = 0; v < 3; ++v)
          acc = fdot2(q1p[v], K1u[v*1152 + row*32 + jk], acc);
        p[k] = acc;
      }
#pragma unroll
      for (int m = 1; m < 8; m <<= 1) {
#pragma unroll
        for (int k = 0; k < 4; ++k) p[k] += __shfl_xor(p[k], m, 64);
      }
      float mx = -1e30f;
#pragma unroll
      for (int k = 0; k < 4; ++k) { p[k] *= 0.25f; if (k < km) mx = fmaxf(mx, p[k]); }
      float aw[4], ssum = 0.f;
#pragma unroll
      for (int k = 0; k < 4; ++k) { aw[k] = (k < km) ? fexp(p[k]-mx) : 0.f; ssum += aw[k]; }
      float inv = frcp(ssum);
      AWp[it][0] = packf16(aw[0]*inv, aw[1]*inv);
      AWp[it][1] = packf16(aw[2]*inv, aw[3]*inv);
      const uint2* rp = (const uint2*)(rhat + (size_t)gt*12);
      uint2 ra = rp[0], rb = rp[1], rc = rp[2];
      u32 rw[6] = {ra.x, ra.y, rb.x, rb.y, rc.x, rc.y};
      h2f o0p = {(_Float16)0.f, (_Float16)0.f};
      h2f o1p0 = o0p, o1p1 = o0p, o1p2 = o0p;
#pragma unroll
      for (int k = 0; k < 4; ++k) {
        int row = lr[k];
        int jk = l32 ^ (((row>>2)&3)<<3);
        float a = aw[k]*inv;
        _Float16 ah = (_Float16)a;
        h2f a2; a2.x = ah; a2.y = ah;
        h2f v0p = __builtin_bit_cast(h2f, V0u[row*32 + jk]);
#pragma unroll
        for (int v = 0; v < 3; ++v) {
          int idx = k*3 + v;
          u32 w = rw[idx>>1];
          u32 hh = (idx&1) ? (w >> 16) : (w & 0xffffu);
          h2f rh2 = __builtin_bit_cast(h2f, (hh << 16) | hh);
          h2f term = a2*(v0p*rh2);
          if (v == 0) o1p0 = term + o1p0;
          else if (v == 1) o1p1 = term + o1p1;
          else o1p2 = term + o1p2;
        }
        o0p = a2*v0p + o0p;
      }
      O0k[it] = __builtin_bit_cast(u32, o0p);
      O1k[it][0] = __builtin_bit_cast(u32, o1p0);
      O1k[it][1] = __builtin_bit_cast(u32, o1p1);
      O1k[it][2] = __builtin_bit_cast(u32, o1p2);
    }
  }
  __syncthreads();   // BAR 2: all K reads done -> K1 slot dead

  // ---- P2b: project V1 into K1's slot (g1f still in regs for waves 0-2) ----
  if (wv < 3) {
    int tb = wv*16;
#pragma unroll
    for (int v = 0; v < 3; ++v)
      projs(g1f[v], base + 5*2048, (u16*)(S+LV1) + v*2304, tb, 36);
  }
  __syncthreads();   // BAR 3: V1 staged

  // ---- P3b: V1-dependent accumulation ----
  {
    const u32* V1u = S + LV1;
    int half = lane >> 5, l32 = lane & 31;
#pragma unroll
    for (int it = 0; it < 4; ++it) {
      int ct = wv*8 + it*2 + half;
      int n = n0 + ct;
      size_t gt = (size_t)b*NN + n;
      int4 nb = *(const int4*)(nbr + n*4);
      int lr[4];
      {
        int xx;
        xx = nb.x - n0 + 2; lr[0] = xx < 0 ? 0 : (xx > 35 ? 35 : xx);
        xx = nb.y - n0 + 2; lr[1] = xx < 0 ? 0 : (xx > 35 ? 35 : xx);
        xx = nb.z - n0 + 2; lr[2] = xx < 0 ? 0 : (xx > 35 ? 35 : xx);
        xx = nb.w - n0 + 2; lr[3] = xx < 0 ? 0 : (xx > 35 ? 35 : xx);
      }
      const uint2* rp = (const uint2*)(rhat + (size_t)gt*12);
      uint2 ra = rp[0], rb = rp[1], rc = rp[2];
      u32 rw[6] = {ra.x, ra.y, rb.x, rb.y, rc.x, rc.y};
      float2 awA = unpk(AWp[it][0]), awB = unpk(AWp[it][1]);
      float af4[4] = {awA.x, awA.y, awB.x, awB.y};
      h2f o0p = __builtin_bit_cast(h2f, O0k[it]);
      h2f o1p0 = __builtin_bit_cast(h2f, O1k[it][0]);
      h2f o1p1 = __builtin_bit_cast(h2f, O1k[it][1]);
      h2f o1p2 = __builtin_bit_cast(h2f, O1k[it][2]);
#pragma unroll
      for (int k = 0; k < 4; ++k) {
        int row = lr[k];
        int jk = l32 ^ (((row>>2)&3)<<3);
        _Float16 ah = (_Float16)af4[k];
        h2f a2; a2.x = ah; a2.y = ah;
        h2f v1p[3], rh2[3];
#pragma unroll
        for (int v = 0; v < 3; ++v) {
          v1p[v] = __builtin_bit_cast(h2f, V1u[v*1152 + row*32 + jk]);
          int idx = k*3 + v;
          u32 w = rw[idx>>1];
          u32 hh = (idx&1) ? (w >> 16) : (w & 0xffffu);
          rh2[v] = __builtin_bit_cast(h2f, (hh << 16) | hh);
        }
        h2f vd = v1p[0]*rh2[0];
        vd = v1p[1]*rh2[1] + vd;
        vd = v1p[2]*rh2[2] + vd;
        o0p  = a2*vd + o0p;
        o1p0 = a2*v1p[0] + o1p0;
        o1p1 = a2*v1p[1] + o1p1;
        o1p2 = a2*v1p[2] + o1p2;
      }
      O0k[it] = __builtin_bit_cast(u32, o0p);
      O1k[it][0] = __builtin_bit_cast(u32, o1p0);
      O1k[it][1] = __builtin_bit_cast(u32, o1p1);
      O1k[it][2] = __builtin_bit_cast(u32, o1p2);
    }
  }
  __syncthreads();   // BAR 4: V1 reads done -> KV region + Q region dead

  // ---- merged write phase: O into KV region; residuals loaded/computed now ----
  {
    u32* o0u = S + LO0q;
    u32* o1u = S + LO1q;
    int half = lane >> 5, l32 = lane & 31;
#pragma unroll
    for (int it = 0; it < 4; ++it) {
      int ct = wv*8 + it*2 + half;
      o0u[ct*36 + l32] = O0k[it];
#pragma unroll
      for (int v = 0; v < 3; ++v)
        o1u[(v*32+ct)*36 + l32] = O1k[it][v];
    }
    uint4* d0 = (uint4*)(S + FR0q);
    uint4* d1 = (uint4*)(S + FR1q);
    if (l == 0) {
      {
        int t0 = tid >> 3, j0 = (tid & 7)*4;
        const float* x3 = x + ((size_t)b*NN + n0 + t0)*3;
        float xv[3] = {x3[0], x3[1], x3[2]};
        u32 tmp[4];
#pragma unroll
        for (int q = 0; q < 4; ++q) {
          int ca = 2*(j0+q), cb = ca+1;
          float va = (ca < TC) ? te2[b*TC+ca] : xv[ca-61];
          float vb = (cb < TC) ? te2[b*TC+cb] : xv[cb-61];
          tmp[q] = packf16(va, vb);
        }
        d0[tid] = make_uint4(tmp[0], tmp[1], tmp[2], tmp[3]);
      }
#pragma unroll
      for (int k = 0; k < 3; ++k) {
        int idx = k*1024 + tid*4;
        int t = idx/96, rem = idx%96, v = rem >> 5, j = rem & 31;
        float xv = x[((size_t)b*NN + n0 + t)*3 + v];
        u32 tmp[4];
#pragma unroll
        for (int q = 0; q < 4; ++q)
          tmp[q] = packf16(xv*win1[2*(j+q)], xv*win1[2*(j+q)+1]);
        d1[k*256 + tid] = make_uint4(tmp[0], tmp[1], tmp[2], tmp[3]);
      }
    } else {
      const u32* s0 = f0i + ((size_t)b*NN + n0)*32;   // 1024 u32 contiguous
      const u32* s1 = f1i + ((size_t)b*NN + n0)*96;   // 3072 u32 contiguous
      d0[tid]       = *(const uint4*)(s0 + tid*4);
      d1[tid]       = *(const uint4*)(s1 + (0*256 + tid)*4);
      d1[256 + tid] = *(const uint4*)(s1 + (1*256 + tid)*4);
      d1[512 + tid] = *(const uint4*)(s1 + (2*256 + tid)*4);
    }
  }
  __syncthreads();   // BAR 5: O + residuals visible

  // ---- P4 prologue: a-frags from O -> regs ----
  int tl16 = (wv & 1)*16;
  h8 a1[3][2]; h8 a0[2];
  if (wv < 2) {
#pragma unroll
    for (int v = 0; v < 3; ++v)
#pragma unroll
      for (int kc = 0; kc < 2; ++kc)
        a1[v][kc] = __builtin_bit_cast(h8, *(const uint4*)(S + LO1q + (v*32 + tl16 + arow)*36 + kc*16 + aq*4));
  } else {
#pragma unroll
    for (int kc = 0; kc < 2; ++kc)
      a0[kc] = __builtin_bit_cast(h8, *(const uint4*)(S + LO0q + (tl16 + arow)*36 + kc*16 + aq*4));
  }
  __syncthreads();   // BAR 6: all a-frag reads done -> O region free for hp

  // ---- P4: out-proj + FF (waves 0-1: f1 path; waves 2-3: f0 path) ----
  {
    const u32* Wf = W16 + 188416 + l*22528;
    const u32* po0f = Wf;
    const u32* po1f = Wf + 2048;
    const u32* pf1f = Wf + 4096;
    const u32* paf  = Wf + 6144;
    const u32* pbf  = Wf + 14336;
    const u32* FR0 = S + FR0q;
    const u32* FR1 = S + FR1q;
    size_t gt0 = (size_t)b*NN + n0 + tl16;
    if (wv < 2) {
      // f1 path: Wo1 + residual -> vnorm -> ff1 + residual -> f1o (or score at l==3)
      float f1m[3][4][4];
#pragma unroll
      for (int v = 0; v < 3; ++v)
#pragma unroll
        for (int nt = 0; nt < 4; ++nt) {
          f4 acc = {0.f, 0.f, 0.f, 0.f};
#pragma unroll
          for (int kc = 0; kc < 2; ++kc) {
            uint4 wb = *(const uint4*)(po1f + (nt*2+kc)*256 + lane*4);
            acc = __builtin_amdgcn_mfma_f32_16x16x32_f16(a1[v][kc], __builtin_bit_cast(h8, wb), acc, 0, 0, 0);
          }
#pragma unroll
          for (int r = 0; r < 4; ++r) {
            int t = tl16 + mb + r;
            float2 pq = unpk(FR1[(t*3+v)*32 + nt*8 + (ncol>>1)]);
            f1m[v][nt][r] = acc[r] + ((ncol&1) ? pq.y : pq.x);
          }
        }
      float vs[4];
#pragma unroll
      for (int r = 0; r < 4; ++r) {
        float ss = 0.f;
#pragma unroll
        for (int v = 0; v < 3; ++v)
#pragma unroll
          for (int nt = 0; nt < 4; ++nt) ss += f1m[v][nt][r]*f1m[v][nt][r];
        ss += __shfl_xor(ss, 1, 64); ss += __shfl_xor(ss, 2, 64);
        ss += __shfl_xor(ss, 4, 64); ss += __shfl_xor(ss, 8, 64);
        vs[r] = frsq(ss*(1.f/64.f) + EPSF);
      }
      // vn overlays this wave's OWN FR1 region (residuals already consumed)
      u32* vn = S + FR1q + wv*1536;
      {
        u16* vnh = (u16*)vn;
#pragma unroll
        for (int v = 0; v < 3; ++v)
#pragma unroll
          for (int nt = 0; nt < 4; ++nt)
#pragma unroll
            for (int r = 0; r < 4; ++r)
              vnh[v*1024 + (mb+r)*64 + ((nt^aq)&3)*16 + ncol] = f16b(f1m[v][nt][r]*vs[r]);
      }
      float wl[3][4], sc[3][4];
      if (l == 3) {
#pragma unroll
        for (int v = 0; v < 3; ++v)
#pragma unroll
          for (int nt = 0; nt < 4; ++nt) { wl[v][nt] = wout[v*64 + nt*16 + ncol]; }
#pragma unroll
        for (int v = 0; v < 3; ++v)
#pragma unroll
          for (int r = 0; r < 4; ++r) sc[v][r] = 0.f;
      }
#pragma unroll
      for (int v = 0; v < 3; ++v)
#pragma unroll
        for (int nt = 0; nt < 4; ++nt) {
          f4 acc = {0.f, 0.f, 0.f, 0.f};
#pragma unroll
          for (int kc = 0; kc < 2; ++kc) {
            int lc = kc*2 + (aq>>1);
            int pc = (lc ^ (arow>>2)) & 3;
            h8 af = __builtin_bit_cast(h8, *(const uint4*)(vn + v*512 + arow*32 + pc*8 + (aq&1)*4));
            uint4 wb = *(const uint4*)(pf1f + (nt*2+kc)*256 + lane*4);
            acc = __builtin_amdgcn_mfma_f32_16x16x32_f16(af, __builtin_bit_cast(h8, wb), acc, 0, 0, 0);
          }
#pragma unroll
          for (int r = 0; r < 4; ++r) {
            size_t gt = gt0 + mb + r;
            float val = acc[r] + f1m[v][nt][r];
            if (l < 3) {
              float par = __shfl_xor(val, 1, 64);
              if (!(ncol & 1))
                f1o[(gt*3+v)*32 + nt*8 + (ncol>>1)] = packf16(val, par);
            } else {
              sc[v][r] += val * wl[v][nt];
            }
          }
        }
      if (l == 3) {
#pragma unroll
        for (int v = 0; v < 3; ++v)
#pragma unroll
          for (int r = 0; r < 4; ++r) {
            float xx = sc[v][r];
            xx += __shfl_xor(xx, 1, 64); xx += __shfl_xor(xx, 2, 64);
            xx += __shfl_xor(xx, 4, 64); xx += __shfl_xor(xx, 8, 64);
            if (ncol == 0) out[(gt0 + mb + r)*3 + v] = xx + bout[v];
          }
      }
    } else if (l < 3) {
      // f0 path: Wo0 + residual -> LN -> ffa/silu -> ffb + residual -> f0o
      float f0m[4][4];
#pragma unroll
      for (int nt = 0; nt < 4; ++nt) {
        f4 acc = {0.f, 0.f, 0.f, 0.f};
#pragma unroll
        for (int kc = 0; kc < 2; ++kc) {
          uint4 wb = *(const uint4*)(po0f + (nt*2+kc)*256 + lane*4);
          acc = __builtin_amdgcn_mfma_f32_16x16x32_f16(a0[kc], __builtin_bit_cast(h8, wb), acc, 0, 0, 0);
        }
#pragma unroll
        for (int r = 0; r < 4; ++r) {
          int t = tl16 + mb + r;
          float2 pq = unpk(FR0[t*32 + nt*8 + (ncol>>1)]);
          f0m[nt][r] = acc[r] + ((ncol&1) ? pq.y : pq.x);
        }
      }
      float mu[4], ri[4];
#pragma unroll
      for (int r = 0; r < 4; ++r) {
        float sg = 0.f, s2 = 0.f;
#pragma unroll
        for (int nt = 0; nt < 4; ++nt) { sg += f0m[nt][r]; s2 += f0m[nt][r]*f0m[nt][r]; }
        sg += __shfl_xor(sg, 1, 64); sg += __shfl_xor(sg, 2, 64);
        sg += __shfl_xor(sg, 4, 64); sg += __shfl_xor(sg, 8, 64);
        s2 += __shfl_xor(s2, 1, 64); s2 += __shfl_xor(s2, 2, 64);
        s2 += __shfl_xor(s2, 4, 64); s2 += __shfl_xor(s2, 8, 64);
        mu[r] = sg*(1.f/64.f);
        ri[r] = frsq(fmaxf(s2*(1.f/64.f)-mu[r]*mu[r], 0.f) + EPSF);
      }
      // gg overlays this wave's OWN FR0 region
      u32* gg = S + FR0q + (wv & 1)*512;
      {
        u16* gh = (u16*)gg;
#pragma unroll
        for (int nt = 0; nt < 4; ++nt)
#pragma unroll
          for (int r = 0; r < 4; ++r)
            gh[(mb+r)*64 + ((nt^aq)&3)*16 + ncol] = f16b((f0m[nt][r]-mu[r])*ri[r]);
      }
      // hp: 16 rows x 256 halves (128 u32), chunk-XOR swizzled; overlays dead O region
      u32* hp = S + KVB + (wv-2)*2048;
      {
        h8 ga[2];
#pragma unroll
        for (int kc = 0; kc < 2; ++kc) {
          int lc = kc*2 + (aq>>1);
          int pc = (lc ^ (arow>>2)) & 3;
          ga[kc] = __builtin_bit_cast(h8, *(const uint4*)(gg + arow*32 + pc*8 + (aq&1)*4));
        }
        u16* hhh = (u16*)hp;
#pragma unroll
        for (int nt16 = 0; nt16 < 16; ++nt16) {
          f4 acc = {0.f, 0.f, 0.f, 0.f};
#pragma unroll
          for (int kc = 0; kc < 2; ++kc) {
            uint4 wb = *(const uint4*)(paf + (nt16*2+kc)*256 + lane*4);
            acc = __builtin_amdgcn_mfma_f32_16x16x32_f16(ga[kc], __builtin_bit_cast(h8, wb), acc, 0, 0, 0);
          }
#pragma unroll
          for (int r = 0; r < 4; ++r) {
            float a = acc[r];
            int row = mb + r;
            int chunk = (nt16*2 + (ncol>>3)) ^ (row & 7);
            hhh[row*256 + chunk*8 + (ncol&7)] = f16b(a * frcp(1.f + fexp(-a)));
          }
        }
      }
#pragma unroll
      for (int nt = 0; nt < 4; ++nt) {
        f4 acc = {0.f, 0.f, 0.f, 0.f};
#pragma unroll
        for (int kc = 0; kc < 8; ++kc) {
          int c = kc*4 + aq;
          h8 af = __builtin_bit_cast(h8, *(const uint4*)(hp + arow*128 + ((c ^ (arow & 7))<<2)));
          uint4 wb = *(const uint4*)(pbf + (nt*8+kc)*256 + lane*4);
          acc = __builtin_amdgcn_mfma_f32_16x16x32_f16(af, __builtin_bit_cast(h8, wb), acc, 0, 0, 0);
        }
#pragma unroll
        for (int r = 0; r < 4; ++r) {
          size_t gt = gt0 + mb + r;
          float val = acc[r] + f0m[nt][r];
          float par = __shfl_xor(val, 1, 64);
          if (!(ncol & 1))
            f0o[gt*32 + nt*8 + (ncol>>1)] = packf16(val, par);
        }
      }
    }
  }
}

extern "C" void kernel_launch(void* const* d_in, const int* in_sizes, int n_in,
                              void* d_out, int out_size, void* d_ws, size_t ws_size,
                              hipStream_t stream) {
  float* out = (float*)d_out;
  static const int exp23[23] = {196608,196608,8,32768,32768,16384,128,7808,61,64,
                                16384,16384,16384,16384,16384,16384,16384,16384,
                                65536,65536,16384,192,3};
  bool ok23 = (n_in == 23), ok22 = (n_in == 22);
  int bad = -1;
  if (ok23) {
    for (int i = 0; i < 23; ++i) if (in_sizes[i] != exp23[i]) { ok23 = false; bad = i; break; }
  }
  if (!ok23 && ok22) {
    for (int i = 0; i < 22; ++i) {
      int want = (i == 0) ? exp23[0] : exp23[i+1];
      if (in_sizes[i] != want) { ok22 = false; if (bad < 0) bad = i; break; }
    }
  } else ok22 = false;
  if (!ok23 && !ok22) {
    k_const<<<768, 256, 0, stream>>>(out, (float)(3000 + (bad < 0 ? 100 + n_in : bad)));
    return;
  }
  int sh = ok23 ? 0 : -1;
  const int* nbr = (const int*)d_in[3 + sh];
  const float* F[20];
  F[0] = (const float*)d_in[0];
  F[1] = (const float*)d_in[2 + sh];
  for (int j = 0; j < 18; ++j) F[2 + j] = (const float*)d_in[5 + sh + j];

  char* ws = (char*)d_ws;
  u32*   W16  = (u32*)ws;                           // 1,114,112 B
  float* te2  = (float*)(ws + 1114112);             // 2,048 B
  u16*   rhat = (u16*)(ws + 1116160);               // 1,572,864 B
  u32*   f0A  = (u32*)(ws + 2689024);               // 8,388,608 B
  u32*   f1A  = (u32*)(ws + 11077632);              // 25,165,824 B
  u32*   f0B  = (u32*)(ws + 36243456);              // 8,388,608 B
  u32*   f1B  = (u32*)(ws + 44632064);              // 25,165,824 B -> end 69,797,888

  WSrc s;
  s.m[0]=F[7]; s.m[1]=F[8]; s.m[2]=F[9]; s.m[3]=F[10]; s.m[4]=F[11]; s.m[5]=F[12];
  s.m[6]=F[13]; s.m[7]=F[14]; s.m[8]=F[17]; s.m[9]=F[15]; s.m[10]=F[16];

  k_prep<<<1096 + BN*4/256, 256, 0, stream>>>(s, W16, F[1], F[2], F[3], F[4], F[5], te2,
                                              F[0], nbr, rhat);
  for (int l = 0; l < LL; ++l) {
    const u32* fi0 = (l & 1) ? f0B : f0A;
    const u32* fi1 = (l & 1) ? f1B : f1A;
    u32*       fo0 = (l & 1) ? f0A : f0B;
    u32*       fo1 = (l & 1) ? f1A : f1B;
    k_layer<<<BN/32, 256, 0, stream>>>(W16, l, fi0, fi1, nbr, rhat, fo0, fo1,
                                       F[18], F[19], out, F[0], F[6], te2);
  }
}

// Round 16
// 342.519 us; speedup vs baseline: 1.1800x; 1.0538x over previous
//
#include <hip/hip_runtime.h>

#define BB 8
#define NN 8192
#define RR 2048
#define LL 4
#define TC 61
#define EPSF 1e-6f
#define BN (BB*NN)
#define OUTN (BN*3)

typedef unsigned short u16;
typedef unsigned int u32;
typedef _Float16 h2f __attribute__((ext_vector_type(2)));
typedef _Float16 h8 __attribute__((ext_vector_type(8)));
typedef float f4 __attribute__((ext_vector_type(4)));

__device__ __forceinline__ u32 packf16(float a, float b) {
  h2f h; h.x = (_Float16)a; h.y = (_Float16)b; return __builtin_bit_cast(u32, h);
}
__device__ __forceinline__ u16 f16b(float a) {
  _Float16 h = (_Float16)a; return __builtin_bit_cast(u16, h);
}
__device__ __forceinline__ float2 unpk(u32 a) {
  h2f h = __builtin_bit_cast(h2f, a); return make_float2((float)h.x, (float)h.y);
}
__device__ __forceinline__ float fdot2(u32 a, u32 b, float c) {
  return __builtin_amdgcn_fdot2(__builtin_bit_cast(h2f, a), __builtin_bit_cast(h2f, b), c, false);
}
__device__ __forceinline__ float frcp(float x) { return __builtin_amdgcn_rcpf(x); }
__device__ __forceinline__ float frsq(float x) { return __builtin_amdgcn_rsqf(x); }
__device__ __forceinline__ float fexp(float x) { return __expf(x); }
__device__ __forceinline__ int kmax_of(int n) {
  int aatom = n & 3, rres = n >> 2;
  return (aatom==0) ? (rres==0 ? 2 : 3)
       : (aatom==1) ? 3
       : (aatom==2) ? (rres==RR-1 ? 3 : 4) : 2;
}

__global__ __launch_bounds__(256) void k_const(float* out, float v) {
  int i = blockIdx.x*256 + threadIdx.x;
  if (i < OUTN) out[i] = v;
}

// ---------- weight pre-pack + te MLP + rhat (merged) ----------
struct WSrc { const float* m[11]; };
__global__ __launch_bounds__(256) void k_prep(WSrc s, u32* W16,
    const float* t, const float* w1, const float* b1,
    const float* w2, const float* b2, float* te2,
    const float* x, const int* nbr, u16* rhat) {
  if (blockIdx.x >= 1096) {               // rhat blocks
    int i = (blockIdx.x - 1096)*256 + threadIdx.x;   // BN*4 items
    int tok = i >> 2, k = i & 3;
    int b = tok >> 13, n = tok & (NN-1);
    int tj = b*NN + nbr[n*4 + k];
    float x0 = x[tok*3+0], x1 = x[tok*3+1], x2 = x[tok*3+2];
    float rx = x[tj*3+0] - x0, ry = x[tj*3+1] - x1, rz = x[tj*3+2] - x2;
    float ir = rsqrtf(rx*rx + ry*ry + rz*rz + EPSF);
    rhat[(size_t)(tok*4+k)*3 + 0] = f16b(rx * ir);
    rhat[(size_t)(tok*4+k)*3 + 1] = f16b(ry * ir);
    rhat[(size_t)(tok*4+k)*3 + 2] = f16b(rz * ir);
    return;
  }
  if (blockIdx.x >= 1088) {               // te blocks: one per batch
    __shared__ float s0[128], s1[128];
    int bb = blockIdx.x - 1088;
    int j = threadIdx.x;
    float tv = t[bb];
    if (j < 128) {
      int i = j & 63;
      float fr = expf(-9.210340371976184f * (float)i * (1.0f/64.0f));
      float em = tv * fr;
      s0[j] = (j < 64) ? sinf(em) : cosf(em);
    }
    __syncthreads();
    if (j < 128) {
      float acc = b1[j];
      for (int i2 = 0; i2 < 128; ++i2) acc += s0[i2] * w1[i2*128 + j];
      s1[j] = acc / (1.f + expf(-acc));
    }
    __syncthreads();
    if (j < TC) {
      float a2 = b2[j];
      for (int i2 = 0; i2 < 128; ++i2) a2 += s1[i2] * w2[i2*TC + j];
      te2[bb*TC + j] = a2;
    }
    return;
  }
  int i = blockIdx.x*256 + threadIdx.x;   // 278528 items
  if (i < 73728) {
    int m = i >> 13, rr = i & 8191, l = rr >> 11, r2 = rr & 2047;
    int c2 = r2 >> 6, col = r2 & 63;
    const float* src = s.m[m] + l*4096;
    W16[i] = packf16(src[(2*c2)*64 + col], src[(2*c2+1)*64 + col]);
  } else if (i < 106496) {
    int j2 = i - 73728; int l = j2 >> 13, r2 = j2 & 8191;
    int c2 = r2 >> 8, j = r2 & 255;
    const float* src = s.m[9] + l*16384;
    W16[i] = packf16(src[(2*c2)*256 + j], src[(2*c2+1)*256 + j]);
  } else if (i < 139264) {
    int j2 = i - 106496; int l = j2 >> 13, r2 = j2 & 8191;
    int jp = r2 >> 6, e = r2 & 63;
    const float* src = s.m[10] + l*16384;
    W16[i] = packf16(src[(2*jp)*64 + e], src[(2*jp+1)*64 + e]);
  } else if (i < 188416) {                // QKV B-frags
    int j2 = i - 139264;
    int l = j2 / 12288, rem = j2 % 12288;
    int m = rem >> 11, r2 = rem & 2047;
    int fb = r2 >> 8, li = r2 & 255;
    int nt = fb >> 1, kc = fb & 1;
    int lane = li >> 2, j = li & 3;
    int c2 = kc*16 + (lane>>4)*4 + j;
    int e  = nt*16 + (lane & 15);
    const float* src = s.m[m] + l*4096;
    W16[i] = packf16(src[(2*c2)*64 + e], src[(2*c2+1)*64 + e]);
  } else {                                // odfb B-frags
    int j2 = i - 188416;
    int l = j2 / 22528, rem = j2 % 22528;
    int li, fb, msel, N;
    const float* srcb;
    if (rem < 6144) {                     // Wo0 / Wo1 / Wff1 (64x64)
      msel = 6 + (rem >> 11);             // 6,7,8
      int r2 = rem & 2047;
      fb = r2 >> 8; li = r2 & 255;
      srcb = s.m[msel] + l*4096; N = 64;
      int nt = fb >> 1, kc = fb & 1;
      int lane = li >> 2, j = li & 3;
      int c2 = kc*16 + (lane>>4)*4 + j;
      int e  = nt*16 + (lane & 15);
      W16[i] = packf16(srcb[(2*c2)*N + e], srcb[(2*c2+1)*N + e]);
    } else if (rem < 14336) {             // ffa (64x256)
      int r2 = rem - 6144;
      fb = r2 >> 8; li = r2 & 255;
      srcb = s.m[9] + l*16384; N = 256;
      int nt = fb >> 1, kc = fb & 1;
      int lane = li >> 2, j = li & 3;
      int c2 = kc*16 + (lane>>4)*4 + j;
      int e  = nt*16 + (lane & 15);
      W16[i] = packf16(srcb[(2*c2)*N + e], srcb[(2*c2+1)*N + e]);
    } else {                              // ffb (256x64), fb = nt*8+kc
      int r2 = rem - 14336;
      fb = r2 >> 8; li = r2 & 255;
      srcb = s.m[10] + l*16384; N = 64;
      int nt = fb >> 3, kc = fb & 7;
      int lane = li >> 2, j = li & 3;
      int c2 = kc*16 + (lane>>4)*4 + j;
      int e  = nt*16 + (lane & 15);
      W16[i] = packf16(srcb[(2*c2)*N + e], srcb[(2*c2+1)*N + e]);
    }
  }
}

// ---------- fully fused per-layer kernel, v15 = v12 (338us champion) + setprio ----------
// v13/v14 (4 blocks/CU phase-split) falsified: register state doesn't fit 128
// VGPR cap without spills (VGPR=64 + 90-119MB scratch WRITE). Reverting to the
// verified v12 structure; only addition is s_setprio(1) around P4 MFMA
// clusters (T5: phase-role split satisfies its prerequisite; zero reg cost).
#define QH  0
#define KRG 4096
#define LK0 (KRG)
#define LV0 (KRG+1152)
#define LK1 (KRG+2304)
#define LV1 (KRG+5760)
#define LO0q (KRG)            // O0: 1152
#define LO1q (KRG+1152)       // O1: 3456
#define FR0q (KRG+4608)       // res f0: 1024
#define FR1q (KRG+5632)       // res f1: 3072
#define LDSU 13312    // 53,248 B -> 3 blocks/CU

__global__ __launch_bounds__(256, 3) void k_layer(const u32* __restrict__ W16, int l,
    const u32* __restrict__ f0i, const u32* __restrict__ f1i,
    const int* __restrict__ nbr, const u16* __restrict__ rhat,
    u32* __restrict__ f0o, u32* __restrict__ f1o,
    const float* __restrict__ wout, const float* __restrict__ bout,
    float* __restrict__ out,
    const float* __restrict__ x, const float* __restrict__ win1,
    const float* __restrict__ te2) {
  __shared__ __align__(16) u32 S[LDSU];
  int tid = threadIdx.x, wv = tid >> 6, lane = tid & 63;
  int arow = lane & 15, aq = lane >> 4;
  int t0g = blockIdx.x * 32;
  int b = t0g >> 13, n0 = t0g & (NN-1);
  const u32 ONE2 = 0x3C003C00u;

  // ---- P0: residual into regs (l==0: computed; else pre-issued loads) ----
  uint4 res0, res1a, res1b, res1c;
  if (l == 0) {
    {
      int t0 = tid >> 3, j0 = (tid & 7)*4;
      const float* x3 = x + ((size_t)b*NN + n0 + t0)*3;
      float xv[3] = {x3[0], x3[1], x3[2]};
      u32 tmp[4];
#pragma unroll
      for (int q = 0; q < 4; ++q) {
        int ca = 2*(j0+q), cb = ca+1;
        float va = (ca < TC) ? te2[b*TC+ca] : xv[ca-61];
        float vb = (cb < TC) ? te2[b*TC+cb] : xv[cb-61];
        tmp[q] = packf16(va, vb);
      }
      res0 = make_uint4(tmp[0], tmp[1], tmp[2], tmp[3]);
    }
    uint4* rr[3] = {&res1a, &res1b, &res1c};
#pragma unroll
    for (int k = 0; k < 3; ++k) {
      int idx = k*1024 + tid*4;
      int t = idx/96, rem = idx%96, v = rem >> 5, j = rem & 31;
      float xv = x[((size_t)b*NN + n0 + t)*3 + v];
      u32 tmp[4];
#pragma unroll
      for (int q = 0; q < 4; ++q)
        tmp[q] = packf16(xv*win1[2*(j+q)], xv*win1[2*(j+q)+1]);
      *rr[k] = make_uint4(tmp[0], tmp[1], tmp[2], tmp[3]);
    }
  } else {
    const u32* s0 = f0i + ((size_t)b*NN + n0)*32;   // 1024 u32 contiguous
    const u32* s1 = f1i + ((size_t)b*NN + n0)*96;   // 3072 u32 contiguous
    res0  = *(const uint4*)(s0 + tid*4);
    res1a = *(const uint4*)(s1 + (0*256 + tid)*4);
    res1b = *(const uint4*)(s1 + (1*256 + tid)*4);
    res1c = *(const uint4*)(s1 + (2*256 + tid)*4);
  }

  // ---- P2: norms in A-frag regs (fdot2/pk) + QKV projections ----
  {
    const u32* base = W16 + 139264 + l*12288;
    int ncol = arow, mb = aq*4;

    auto ldraw = [&](int hr0, u32* r0, u32 (*r1)[8]) {
      int n = n0 - 2 + hr0 + arow;
      n = n < 0 ? 0 : (n > NN-1 ? NN-1 : n);
      size_t gt = (size_t)b*NN + n;
      if (l == 0) {
        const float* x3 = x + gt*3;
        float xv[3] = {x3[0], x3[1], x3[2]};
#pragma unroll
        for (int i = 0; i < 8; ++i) {
          int j = (i < 4) ? (aq*4+i) : (16 + aq*4 + (i-4));
          int ca = 2*j, cb = ca+1;
          float va = (ca < TC) ? te2[b*TC+ca] : xv[ca-61];
          float vb = (cb < TC) ? te2[b*TC+cb] : xv[cb-61];
          r0[i] = packf16(va, vb);
          float wa = win1[ca], wb = win1[cb];
#pragma unroll
          for (int v = 0; v < 3; ++v)
            r1[v][i] = packf16(xv[v]*wa, xv[v]*wb);
        }
      } else {
        *(uint4*)(r0)   = *(const uint4*)(f0i + gt*32 + aq*4);
        *(uint4*)(r0+4) = *(const uint4*)(f0i + gt*32 + 16 + aq*4);
#pragma unroll
        for (int v = 0; v < 3; ++v) {
          *(uint4*)(r1[v])   = *(const uint4*)(f1i + (gt*3+v)*32 + aq*4);
          *(uint4*)(r1[v]+4) = *(const uint4*)(f1i + (gt*3+v)*32 + 16 + aq*4);
        }
      }
    };

    auto mknorm = [&](const u32* r0, const u32 (*r1)[8], h8* g0f, h8 (*g1f)[2]) {
      float s = 0.f, s2 = 0.f;
#pragma unroll
      for (int i = 0; i < 8; ++i) { s = fdot2(r0[i], ONE2, s); s2 = fdot2(r0[i], r0[i], s2); }
      s  += __shfl_xor(s, 16, 64);  s  += __shfl_xor(s, 32, 64);
      s2 += __shfl_xor(s2, 16, 64); s2 += __shfl_xor(s2, 32, 64);
      float mu = s*(1.f/64.f);
      float ri = frsq(fmaxf(s2*(1.f/64.f)-mu*mu, 0.f) + EPSF);
      _Float16 rih = (_Float16)ri, bih = (_Float16)(-mu*ri);
      h2f scv; scv.x = rih; scv.y = rih;
      h2f biv; biv.x = bih; biv.y = bih;
#pragma unroll
      for (int kc = 0; kc < 2; ++kc) {
        u32 t0[4];
#pragma unroll
        for (int i = 0; i < 4; ++i) {
          h2f g = __builtin_bit_cast(h2f, r0[kc*4+i]) * scv + biv;
          t0[i] = __builtin_bit_cast(u32, g);
        }
        g0f[kc] = __builtin_bit_cast(h8, make_uint4(t0[0], t0[1], t0[2], t0[3]));
      }
      float ss = 0.f;
#pragma unroll
      for (int v = 0; v < 3; ++v)
#pragma unroll
        for (int i = 0; i < 8; ++i) ss = fdot2(r1[v][i], r1[v][i], ss);
      ss += __shfl_xor(ss, 16, 64); ss += __shfl_xor(ss, 32, 64);
      float vs = frsq(ss*(1.f/64.f) + EPSF);
      _Float16 vsh = (_Float16)vs;
      h2f vsv; vsv.x = vsh; vsv.y = vsh;
#pragma unroll
      for (int v = 0; v < 3; ++v)
#pragma unroll
        for (int kc = 0; kc < 2; ++kc) {
          u32 t1[4];
#pragma unroll
          for (int i = 0; i < 4; ++i) {
            h2f g = __builtin_bit_cast(h2f, r1[v][kc*4+i]) * vsv;
            t1[i] = __builtin_bit_cast(u32, g);
          }
          g1f[v][kc] = __builtin_bit_cast(h8, make_uint4(t1[0], t1[1], t1[2], t1[3]));
        }
    };

    auto projs = [&](const h8* afr, const u32* wM, u16* outh, int ob, int rmax) {
#pragma unroll
      for (int nt = 0; nt < 4; ++nt) {
        f4 acc = {0.f, 0.f, 0.f, 0.f};
#pragma unroll
        for (int kc = 0; kc < 2; ++kc) {
          uint4 wb = *(const uint4*)(wM + (nt*2+kc)*256 + lane*4);
          acc = __builtin_amdgcn_mfma_f32_16x16x32_f16(afr[kc], __builtin_bit_cast(h8, wb), acc, 0, 0, 0);
        }
        int ex = ((nt ^ aq)&3)*16 + ncol;   // aq-XOR swizzle
#pragma unroll
        for (int r = 0; r < 4; ++r) {
          int orow = ob + mb + r;
          if (orow < rmax) outh[orow*64 + ex] = f16b(acc[r]);
        }
      }
    };

    h8 g0f[2]; h8 g1f[3][2];
    if (wv < 3) {
      int tb = wv*16;
      u32 r0[8]; u32 r1[3][8];
      ldraw(tb, r0, r1);
      mknorm(r0, r1, g0f, g1f);
      projs(g0f, base + 1*2048, (u16*)(S+LK0), tb, 36);
      projs(g0f, base + 2*2048, (u16*)(S+LV0), tb, 36);
#pragma unroll
      for (int v = 0; v < 3; ++v) {
        projs(g1f[v], base + 4*2048, (u16*)(S+LK1) + v*2304, tb, 36);
        projs(g1f[v], base + 5*2048, (u16*)(S+LV1) + v*2304, tb, 36);
      }
    } else {
      u32 r0a[8], r1a[3][8], r0b[8], r1b[3][8];
      ldraw(2, r0a, r1a);        // both tiles' loads issue before any compute
      ldraw(18, r0b, r1b);
      mknorm(r0a, r1a, g0f, g1f);
      projs(g0f, base, (u16*)(S+QH), 0, 32);
#pragma unroll
      for (int v = 0; v < 3; ++v)
        projs(g1f[v], base + 3*2048, (u16*)(S+1024) + v*2048, 0, 32);
      mknorm(r0b, r1b, g0f, g1f);
      projs(g0f, base, (u16*)(S+QH), 16, 32);
#pragma unroll
      for (int v = 0; v < 3; ++v)
        projs(g1f[v], base + 3*2048, (u16*)(S+1024) + v*2048, 16, 32);
    }
  }
  __syncthreads();   // BAR 1: Q/K/V staged

  // ---- P3: attention, packed f16 end-to-end: 2 ch/lane, 2 tokens/iter ----
  u32 O0k[4], O1k[4][3];
  {
    const u32* Q0u = S + QH;
    const u32* Q1u = S + 1024;
    const u32* K0u = S + LK0;
    const u32* V0u = S + LV0;
    const u32* K1u = S + LK1;
    const u32* V1u = S + LV1;
    int half = lane >> 5, l32 = lane & 31;
#pragma unroll
    for (int it = 0; it < 4; ++it) {
      int ct = wv*8 + it*2 + half;
      int n = n0 + ct;
      size_t gt = (size_t)b*NN + n;
      int km = kmax_of(n);
      int4 nb = *(const int4*)(nbr + n*4);
      int lr[4];
      {
        int xx;
        xx = nb.x - n0 + 2; lr[0] = xx < 0 ? 0 : (xx > 35 ? 35 : xx);
        xx = nb.y - n0 + 2; lr[1] = xx < 0 ? 0 : (xx > 35 ? 35 : xx);
        xx = nb.z - n0 + 2; lr[2] = xx < 0 ? 0 : (xx > 35 ? 35 : xx);
        xx = nb.w - n0 + 2; lr[3] = xx < 0 ? 0 : (xx > 35 ? 35 : xx);
      }
      int jq = l32 ^ (((ct>>2)&3)<<3);
      u32 q0p = Q0u[ct*32 + jq];
      u32 q1p[3];
#pragma unroll
      for (int v = 0; v < 3; ++v) q1p[v] = Q1u[v*1024 + ct*32 + jq];
      float p[4];
#pragma unroll
      for (int k = 0; k < 4; ++k) {
        int row = lr[k];
        int jk = l32 ^ (((row>>2)&3)<<3);
        float acc = fdot2(q0p, K0u[row*32 + jk], 0.f);
#pragma unroll
        for (int v = 0; v < 3; ++v)
          acc = fdot2(q1p[v], K1u[v*1152 + row*32 + jk], acc);
        p[k] = acc;
      }
#pragma unroll
      for (int m = 1; m < 8; m <<= 1) {
#pragma unroll
        for (int k = 0; k < 4; ++k) p[k] += __shfl_xor(p[k], m, 64);
      }
      float mx = -1e30f;
#pragma unroll
      for (int k = 0; k < 4; ++k) { p[k] *= 0.25f; if (k < km) mx = fmaxf(mx, p[k]); }
      float aw[4], ssum = 0.f;
#pragma unroll
      for (int k = 0; k < 4; ++k) { aw[k] = (k < km) ? fexp(p[k]-mx) : 0.f; ssum += aw[k]; }
      float inv = frcp(ssum);
      const uint2* rp = (const uint2*)(rhat + (size_t)gt*12);
      uint2 ra = rp[0], rb = rp[1], rc = rp[2];
      u32 rw[6] = {ra.x, ra.y, rb.x, rb.y, rc.x, rc.y};
      h2f o0p = {(_Float16)0.f, (_Float16)0.f};
      h2f o1p0 = o0p, o1p1 = o0p, o1p2 = o0p;
#pragma unroll
      for (int k = 0; k < 4; ++k) {
        int row = lr[k];
        int jk = l32 ^ (((row>>2)&3)<<3);
        float a = aw[k]*inv;
        _Float16 ah = (_Float16)a;
        h2f a2; a2.x = ah; a2.y = ah;
        h2f v0p = __builtin_bit_cast(h2f, V0u[row*32 + jk]);
        h2f v1p[3], rh2[3];
#pragma unroll
        for (int v = 0; v < 3; ++v) {
          v1p[v] = __builtin_bit_cast(h2f, V1u[v*1152 + row*32 + jk]);
          int idx = k*3 + v;
          u32 w = rw[idx>>1];
          u32 hh = (idx&1) ? (w >> 16) : (w & 0xffffu);
          rh2[v] = __builtin_bit_cast(h2f, (hh << 16) | hh);
        }
        h2f vd = v1p[0]*rh2[0];
        vd = v1p[1]*rh2[1] + vd;
        vd = v1p[2]*rh2[2] + vd;
        o0p  = a2*(v0p + vd) + o0p;
        o1p0 = a2*(v0p*rh2[0] + v1p[0]) + o1p0;
        o1p1 = a2*(v0p*rh2[1] + v1p[1]) + o1p1;
        o1p2 = a2*(v0p*rh2[2] + v1p[2]) + o1p2;
      }
      O0k[it] = __builtin_bit_cast(u32, o0p);
      O1k[it][0] = __builtin_bit_cast(u32, o1p0);
      O1k[it][1] = __builtin_bit_cast(u32, o1p1);
      O1k[it][2] = __builtin_bit_cast(u32, o1p2);
    }
  }
  __syncthreads();   // BAR 2: K/V reads done -> region dead

  // ---- merged write phase: O + residuals into K-region ----
  {
    u32* o0u = S + LO0q;
    u32* o1u = S + LO1q;
    int half = lane >> 5, l32 = lane & 31;
#pragma unroll
    for (int it = 0; it < 4; ++it) {
      int ct = wv*8 + it*2 + half;
      o0u[ct*36 + l32] = O0k[it];
#pragma unroll
      for (int v = 0; v < 3; ++v)
        o1u[(v*32+ct)*36 + l32] = O1k[it][v];
    }
    uint4* d0 = (uint4*)(S + FR0q);
    d0[tid] = res0;
    uint4* d1 = (uint4*)(S + FR1q);
    d1[tid]       = res1a;
    d1[256 + tid] = res1b;
    d1[512 + tid] = res1c;
  }
  __syncthreads();   // BAR 3: O + residuals visible

  // ---- P4: out-proj + FF (waves 0-1: f1 path; waves 2-3: f0 path) ----
  {
    int tl16 = (wv & 1)*16;
    int ncol = arow, mb = aq*4;
    const u32* Wf = W16 + 188416 + l*22528;
    const u32* po0f = Wf;
    const u32* po1f = Wf + 2048;
    const u32* pf1f = Wf + 4096;
    const u32* paf  = Wf + 6144;
    const u32* pbf  = Wf + 14336;
    const u32* FR0 = S + FR0q;
    const u32* FR1 = S + FR1q;
    size_t gt0 = (size_t)b*NN + n0 + tl16;
    if (wv < 2) {
      // f1 path: Wo1 + residual -> vnorm -> ff1 + residual -> f1o (or score at l==3)
      h8 a1[3][2];
#pragma unroll
      for (int v = 0; v < 3; ++v)
#pragma unroll
        for (int kc = 0; kc < 2; ++kc)
          a1[v][kc] = __builtin_bit_cast(h8, *(const uint4*)(S + LO1q + (v*32 + tl16 + arow)*36 + kc*16 + aq*4));
      float f1m[3][4][4];
      __builtin_amdgcn_s_setprio(1);
#pragma unroll
      for (int v = 0; v < 3; ++v)
#pragma unroll
        for (int nt = 0; nt < 4; ++nt) {
          f4 acc = {0.f, 0.f, 0.f, 0.f};
#pragma unroll
          for (int kc = 0; kc < 2; ++kc) {
            uint4 wb = *(const uint4*)(po1f + (nt*2+kc)*256 + lane*4);
            acc = __builtin_amdgcn_mfma_f32_16x16x32_f16(a1[v][kc], __builtin_bit_cast(h8, wb), acc, 0, 0, 0);
          }
#pragma unroll
          for (int r = 0; r < 4; ++r) {
            int t = tl16 + mb + r;
            float2 pq = unpk(FR1[(t*3+v)*32 + nt*8 + (ncol>>1)]);
            f1m[v][nt][r] = acc[r] + ((ncol&1) ? pq.y : pq.x);
          }
        }
      __builtin_amdgcn_s_setprio(0);
      float vs[4];
#pragma unroll
      for (int r = 0; r < 4; ++r) {
        float ss = 0.f;
#pragma unroll
        for (int v = 0; v < 3; ++v)
#pragma unroll
          for (int nt = 0; nt < 4; ++nt) ss += f1m[v][nt][r]*f1m[v][nt][r];
        ss += __shfl_xor(ss, 1, 64); ss += __shfl_xor(ss, 2, 64);
        ss += __shfl_xor(ss, 4, 64); ss += __shfl_xor(ss, 8, 64);
        vs[r] = frsq(ss*(1.f/64.f) + EPSF);
      }
      // vn overlays this wave's OWN FR1 region (residuals already consumed)
      u32* vn = S + FR1q + wv*1536;
      {
        u16* vnh = (u16*)vn;
#pragma unroll
        for (int v = 0; v < 3; ++v)
#pragma unroll
          for (int nt = 0; nt < 4; ++nt)
#pragma unroll
            for (int r = 0; r < 4; ++r)
              vnh[v*1024 + (mb+r)*64 + ((nt^aq)&3)*16 + ncol] = f16b(f1m[v][nt][r]*vs[r]);
      }
      float wl[3][4], sc[3][4];
      if (l == 3) {
#pragma unroll
        for (int v = 0; v < 3; ++v)
#pragma unroll
          for (int nt = 0; nt < 4; ++nt) { wl[v][nt] = wout[v*64 + nt*16 + ncol]; }
#pragma unroll
        for (int v = 0; v < 3; ++v)
#pragma unroll
          for (int r = 0; r < 4; ++r) sc[v][r] = 0.f;
      }
      __builtin_amdgcn_s_setprio(1);
#pragma unroll
      for (int v = 0; v < 3; ++v)
#pragma unroll
        for (int nt = 0; nt < 4; ++nt) {
          f4 acc = {0.f, 0.f, 0.f, 0.f};
#pragma unroll
          for (int kc = 0; kc < 2; ++kc) {
            int lc = kc*2 + (aq>>1);
            int pc = (lc ^ (arow>>2)) & 3;
            h8 af = __builtin_bit_cast(h8, *(const uint4*)(vn + v*512 + arow*32 + pc*8 + (aq&1)*4));
            uint4 wb = *(const uint4*)(pf1f + (nt*2+kc)*256 + lane*4);
            acc = __builtin_amdgcn_mfma_f32_16x16x32_f16(af, __builtin_bit_cast(h8, wb), acc, 0, 0, 0);
          }
#pragma unroll
          for (int r = 0; r < 4; ++r) {
            size_t gt = gt0 + mb + r;
            float val = acc[r] + f1m[v][nt][r];
            if (l < 3) {
              float par = __shfl_xor(val, 1, 64);
              if (!(ncol & 1))
                f1o[(gt*3+v)*32 + nt*8 + (ncol>>1)] = packf16(val, par);
            } else {
              sc[v][r] += val * wl[v][nt];
            }
          }
        }
      __builtin_amdgcn_s_setprio(0);
      if (l == 3) {
#pragma unroll
        for (int v = 0; v < 3; ++v)
#pragma unroll
          for (int r = 0; r < 4; ++r) {
            float xx = sc[v][r];
            xx += __shfl_xor(xx, 1, 64); xx += __shfl_xor(xx, 2, 64);
            xx += __shfl_xor(xx, 4, 64); xx += __shfl_xor(xx, 8, 64);
            if (ncol == 0) out[(gt0 + mb + r)*3 + v] = xx + bout[v];
          }
      }
    } else if (l < 3) {
      // f0 path: Wo0 + residual -> LN -> ffa/silu -> ffb + residual -> f0o
      h8 a0[2];
#pragma unroll
      for (int kc = 0; kc < 2; ++kc)
        a0[kc] = __builtin_bit_cast(h8, *(const uint4*)(S + LO0q + (tl16 + arow)*36 + kc*16 + aq*4));
      float f0m[4][4];
      __builtin_amdgcn_s_setprio(1);
#pragma unroll
      for (int nt = 0; nt < 4; ++nt) {
        f4 acc = {0.f, 0.f, 0.f, 0.f};
#pragma unroll
        for (int kc = 0; kc < 2; ++kc) {
          uint4 wb = *(const uint4*)(po0f + (nt*2+kc)*256 + lane*4);
          acc = __builtin_amdgcn_mfma_f32_16x16x32_f16(a0[kc], __builtin_bit_cast(h8, wb), acc, 0, 0, 0);
        }
#pragma unroll
        for (int r = 0; r < 4; ++r) {
          int t = tl16 + mb + r;
          float2 pq = unpk(FR0[t*32 + nt*8 + (ncol>>1)]);
          f0m[nt][r] = acc[r] + ((ncol&1) ? pq.y : pq.x);
        }
      }
      __builtin_amdgcn_s_setprio(0);
      float mu[4], ri[4];
#pragma unroll
      for (int r = 0; r < 4; ++r) {
        float sg = 0.f, s2 = 0.f;
#pragma unroll
        for (int nt = 0; nt < 4; ++nt) { sg += f0m[nt][r]; s2 += f0m[nt][r]*f0m[nt][r]; }
        sg += __shfl_xor(sg, 1, 64); sg += __shfl_xor(sg, 2, 64);
        sg += __shfl_xor(sg, 4, 64); sg += __shfl_xor(sg, 8, 64);
        s2 += __shfl_xor(s2, 1, 64); s2 += __shfl_xor(s2, 2, 64);
        s2 += __shfl_xor(s2, 4, 64); s2 += __shfl_xor(s2, 8, 64);
        mu[r] = sg*(1.f/64.f);
        ri[r] = frsq(fmaxf(s2*(1.f/64.f)-mu[r]*mu[r], 0.f) + EPSF);
      }
      // gg overlays this wave's OWN FR0 region
      u32* gg = S + FR0q + (wv & 1)*512;
      {
        u16* gh = (u16*)gg;
#pragma unroll
        for (int nt = 0; nt < 4; ++nt)
#pragma unroll
          for (int r = 0; r < 4; ++r)
            gh[(mb+r)*64 + ((nt^aq)&3)*16 + ncol] = f16b((f0m[nt][r]-mu[r])*ri[r]);
      }
      // hp: 16 rows x 256 halves (128 u32), chunk-XOR swizzled; fits 2x2048 in Q region
      u32* hp = S + (wv-2)*2048;
      {
        h8 ga[2];
#pragma unroll
        for (int kc = 0; kc < 2; ++kc) {
          int lc = kc*2 + (aq>>1);
          int pc = (lc ^ (arow>>2)) & 3;
          ga[kc] = __builtin_bit_cast(h8, *(const uint4*)(gg + arow*32 + pc*8 + (aq&1)*4));
        }
        u16* hhh = (u16*)hp;
        __builtin_amdgcn_s_setprio(1);
#pragma unroll
        for (int nt16 = 0; nt16 < 16; ++nt16) {
          f4 acc = {0.f, 0.f, 0.f, 0.f};
#pragma unroll
          for (int kc = 0; kc < 2; ++kc) {
            uint4 wb = *(const uint4*)(paf + (nt16*2+kc)*256 + lane*4);
            acc = __builtin_amdgcn_mfma_f32_16x16x32_f16(ga[kc], __builtin_bit_cast(h8, wb), acc, 0, 0, 0);
          }
#pragma unroll
          for (int r = 0; r < 4; ++r) {
            float a = acc[r];
            int row = mb + r;
            int chunk = (nt16*2 + (ncol>>3)) ^ (row & 7);
            hhh[row*256 + chunk*8 + (ncol&7)] = f16b(a * frcp(1.f + fexp(-a)));
          }
        }
        __builtin_amdgcn_s_setprio(0);
      }
      __builtin_amdgcn_s_setprio(1);
#pragma unroll
      for (int nt = 0; nt < 4; ++nt) {
        f4 acc = {0.f, 0.f, 0.f, 0.f};
#pragma unroll
        for (int kc = 0; kc < 8; ++kc) {
          int c = kc*4 + aq;
          h8 af = __builtin_bit_cast(h8, *(const uint4*)(hp + arow*128 + ((c ^ (arow & 7))<<2)));
          uint4 wb = *(const uint4*)(pbf + (nt*8+kc)*256 + lane*4);
          acc = __builtin_amdgcn_mfma_f32_16x16x32_f16(af, __builtin_bit_cast(h8, wb), acc, 0, 0, 0);
        }
#pragma unroll
        for (int r = 0; r < 4; ++r) {
          size_t gt = gt0 + mb + r;
          float val = acc[r] + f0m[nt][r];
          float par = __shfl_xor(val, 1, 64);
          if (!(ncol & 1))
            f0o[gt*32 + nt*8 + (ncol>>1)] = packf16(val, par);
        }
      }
      __builtin_amdgcn_s_setprio(0);
    }
  }
}

extern "C" void kernel_launch(void* const* d_in, const int* in_sizes, int n_in,
                              void* d_out, int out_size, void* d_ws, size_t ws_size,
                              hipStream_t stream) {
  float* out = (float*)d_out;
  static const int exp23[23] = {196608,196608,8,32768,32768,16384,128,7808,61,64,
                                16384,16384,16384,16384,16384,16384,16384,16384,
                                65536,65536,16384,192,3};
  bool ok23 = (n_in == 23), ok22 = (n_in == 22);
  int bad = -1;
  if (ok23) {
    for (int i = 0; i < 23; ++i) if (in_sizes[i] != exp23[i]) { ok23 = false; bad = i; break; }
  }
  if (!ok23 && ok22) {
    for (int i = 0; i < 22; ++i) {
      int want = (i == 0) ? exp23[0] : exp23[i+1];
      if (in_sizes[i] != want) { ok22 = false; if (bad < 0) bad = i; break; }
    }
  } else ok22 = false;
  if (!ok23 && !ok22) {
    k_const<<<768, 256, 0, stream>>>(out, (float)(3000 + (bad < 0 ? 100 + n_in : bad)));
    return;
  }
  int sh = ok23 ? 0 : -1;
  const int* nbr = (const int*)d_in[3 + sh];
  const float* F[20];
  F[0] = (const float*)d_in[0];
  F[1] = (const float*)d_in[2 + sh];
  for (int j = 0; j < 18; ++j) F[2 + j] = (const float*)d_in[5 + sh + j];

  char* ws = (char*)d_ws;
  u32*   W16  = (u32*)ws;                           // 1,114,112 B
  float* te2  = (float*)(ws + 1114112);             // 2,048 B
  u16*   rhat = (u16*)(ws + 1116160);               // 1,572,864 B
  u32*   f0A  = (u32*)(ws + 2689024);               // 8,388,608 B
  u32*   f1A  = (u32*)(ws + 11077632);              // 25,165,824 B
  u32*   f0B  = (u32*)(ws + 36243456);              // 8,388,608 B
  u32*   f1B  = (u32*)(ws + 44632064);              // 25,165,824 B -> end 69,797,888

  WSrc s;
  s.m[0]=F[7]; s.m[1]=F[8]; s.m[2]=F[9]; s.m[3]=F[10]; s.m[4]=F[11]; s.m[5]=F[12];
  s.m[6]=F[13]; s.m[7]=F[14]; s.m[8]=F[17]; s.m[9]=F[15]; s.m[10]=F[16];

  k_prep<<<1096 + BN*4/256, 256, 0, stream>>>(s, W16, F[1], F[2], F[3], F[4], F[5], te2,
                                              F[0], nbr, rhat);
  for (int l = 0; l < LL; ++l) {
    const u32* fi0 = (l & 1) ? f0B : f0A;
    const u32* fi1 = (l & 1) ? f1B : f1A;
    u32*       fo0 = (l & 1) ? f0A : f0B;
    u32*       fo1 = (l & 1) ? f1A : f1B;
    k_layer<<<BN/32, 256, 0, stream>>>(W16, l, fi0, fi1, nbr, rhat, fo0, fo1,
                                       F[18], F[19], out, F[0], F[6], te2);
  }
}

// Round 17
// 337.707 us; speedup vs baseline: 1.1968x; 1.0143x over previous
//
#include <hip/hip_runtime.h>

#define BB 8
#define NN 8192
#define RR 2048
#define LL 4
#define TC 61
#define EPSF 1e-6f
#define BN (BB*NN)
#define OUTN (BN*3)

typedef unsigned short u16;
typedef unsigned int u32;
typedef _Float16 h2f __attribute__((ext_vector_type(2)));
typedef _Float16 h8 __attribute__((ext_vector_type(8)));
typedef float f4 __attribute__((ext_vector_type(4)));

__device__ __forceinline__ u32 packf16(float a, float b) {
  h2f h; h.x = (_Float16)a; h.y = (_Float16)b; return __builtin_bit_cast(u32, h);
}
__device__ __forceinline__ u16 f16b(float a) {
  _Float16 h = (_Float16)a; return __builtin_bit_cast(u16, h);
}
__device__ __forceinline__ float2 unpk(u32 a) {
  h2f h = __builtin_bit_cast(h2f, a); return make_float2((float)h.x, (float)h.y);
}
__device__ __forceinline__ float fdot2(u32 a, u32 b, float c) {
  return __builtin_amdgcn_fdot2(__builtin_bit_cast(h2f, a), __builtin_bit_cast(h2f, b), c, false);
}
__device__ __forceinline__ float frcp(float x) { return __builtin_amdgcn_rcpf(x); }
__device__ __forceinline__ float frsq(float x) { return __builtin_amdgcn_rsqf(x); }
__device__ __forceinline__ float fexp(float x) { return __expf(x); }
__device__ __forceinline__ int kmax_of(int n) {
  int aatom = n & 3, rres = n >> 2;
  return (aatom==0) ? (rres==0 ? 2 : 3)
       : (aatom==1) ? 3
       : (aatom==2) ? (rres==RR-1 ? 3 : 4) : 2;
}

__global__ __launch_bounds__(256) void k_const(float* out, float v) {
  int i = blockIdx.x*256 + threadIdx.x;
  if (i < OUTN) out[i] = v;
}

// ---------- weight pre-pack + te MLP + rhat (merged) ----------
struct WSrc { const float* m[11]; };
__global__ __launch_bounds__(256) void k_prep(WSrc s, u32* W16,
    const float* t, const float* w1, const float* b1,
    const float* w2, const float* b2, float* te2,
    const float* x, const int* nbr, u16* rhat) {
  if (blockIdx.x >= 1096) {               // rhat blocks
    int i = (blockIdx.x - 1096)*256 + threadIdx.x;   // BN*4 items
    int tok = i >> 2, k = i & 3;
    int b = tok >> 13, n = tok & (NN-1);
    int tj = b*NN + nbr[n*4 + k];
    float x0 = x[tok*3+0], x1 = x[tok*3+1], x2 = x[tok*3+2];
    float rx = x[tj*3+0] - x0, ry = x[tj*3+1] - x1, rz = x[tj*3+2] - x2;
    float ir = rsqrtf(rx*rx + ry*ry + rz*rz + EPSF);
    rhat[(size_t)(tok*4+k)*3 + 0] = f16b(rx * ir);
    rhat[(size_t)(tok*4+k)*3 + 1] = f16b(ry * ir);
    rhat[(size_t)(tok*4+k)*3 + 2] = f16b(rz * ir);
    return;
  }
  if (blockIdx.x >= 1088) {               // te blocks: one per batch
    __shared__ float s0[128], s1[128];
    int bb = blockIdx.x - 1088;
    int j = threadIdx.x;
    float tv = t[bb];
    if (j < 128) {
      int i = j & 63;
      float fr = expf(-9.210340371976184f * (float)i * (1.0f/64.0f));
      float em = tv * fr;
      s0[j] = (j < 64) ? sinf(em) : cosf(em);
    }
    __syncthreads();
    if (j < 128) {
      float acc = b1[j];
      for (int i2 = 0; i2 < 128; ++i2) acc += s0[i2] * w1[i2*128 + j];
      s1[j] = acc / (1.f + expf(-acc));
    }
    __syncthreads();
    if (j < TC) {
      float a2 = b2[j];
      for (int i2 = 0; i2 < 128; ++i2) a2 += s1[i2] * w2[i2*TC + j];
      te2[bb*TC + j] = a2;
    }
    return;
  }
  int i = blockIdx.x*256 + threadIdx.x;   // 278528 items
  if (i < 73728) {
    int m = i >> 13, rr = i & 8191, l = rr >> 11, r2 = rr & 2047;
    int c2 = r2 >> 6, col = r2 & 63;
    const float* src = s.m[m] + l*4096;
    W16[i] = packf16(src[(2*c2)*64 + col], src[(2*c2+1)*64 + col]);
  } else if (i < 106496) {
    int j2 = i - 73728; int l = j2 >> 13, r2 = j2 & 8191;
    int c2 = r2 >> 8, j = r2 & 255;
    const float* src = s.m[9] + l*16384;
    W16[i] = packf16(src[(2*c2)*256 + j], src[(2*c2+1)*256 + j]);
  } else if (i < 139264) {
    int j2 = i - 106496; int l = j2 >> 13, r2 = j2 & 8191;
    int jp = r2 >> 6, e = r2 & 63;
    const float* src = s.m[10] + l*16384;
    W16[i] = packf16(src[(2*jp)*64 + e], src[(2*jp+1)*64 + e]);
  } else if (i < 188416) {                // QKV B-frags
    int j2 = i - 139264;
    int l = j2 / 12288, rem = j2 % 12288;
    int m = rem >> 11, r2 = rem & 2047;
    int fb = r2 >> 8, li = r2 & 255;
    int nt = fb >> 1, kc = fb & 1;
    int lane = li >> 2, j = li & 3;
    int c2 = kc*16 + (lane>>4)*4 + j;
    int e  = nt*16 + (lane & 15);
    const float* src = s.m[m] + l*4096;
    W16[i] = packf16(src[(2*c2)*64 + e], src[(2*c2+1)*64 + e]);
  } else {                                // odfb B-frags
    int j2 = i - 188416;
    int l = j2 / 22528, rem = j2 % 22528;
    int li, fb, msel, N;
    const float* srcb;
    if (rem < 6144) {                     // Wo0 / Wo1 / Wff1 (64x64)
      msel = 6 + (rem >> 11);             // 6,7,8
      int r2 = rem & 2047;
      fb = r2 >> 8; li = r2 & 255;
      srcb = s.m[msel] + l*4096; N = 64;
      int nt = fb >> 1, kc = fb & 1;
      int lane = li >> 2, j = li & 3;
      int c2 = kc*16 + (lane>>4)*4 + j;
      int e  = nt*16 + (lane & 15);
      W16[i] = packf16(srcb[(2*c2)*N + e], srcb[(2*c2+1)*N + e]);
    } else if (rem < 14336) {             // ffa (64x256)
      int r2 = rem - 6144;
      fb = r2 >> 8; li = r2 & 255;
      srcb = s.m[9] + l*16384; N = 256;
      int nt = fb >> 1, kc = fb & 1;
      int lane = li >> 2, j = li & 3;
      int c2 = kc*16 + (lane>>4)*4 + j;
      int e  = nt*16 + (lane & 15);
      W16[i] = packf16(srcb[(2*c2)*N + e], srcb[(2*c2+1)*N + e]);
    } else {                              // ffb (256x64), fb = nt*8+kc
      int r2 = rem - 14336;
      fb = r2 >> 8; li = r2 & 255;
      srcb = s.m[10] + l*16384; N = 64;
      int nt = fb >> 3, kc = fb & 7;
      int lane = li >> 2, j = li & 3;
      int c2 = kc*16 + (lane>>4)*4 + j;
      int e  = nt*16 + (lane & 15);
      W16[i] = packf16(srcb[(2*c2)*N + e], srcb[(2*c2+1)*N + e]);
    }
  }
}

// ---------- fully fused per-layer kernel, v16 = v12 exactly (338us champion) ----------
// v15's setprio regressed (k_layer 69->92us: waves are lockstep behind BAR3,
// so priority distorts cross-block scheduling instead of arbitrating a
// role-split). Final kernel = verified v12 structure, no setprio.
#define QH  0
#define KRG 4096
#define LK0 (KRG)
#define LV0 (KRG+1152)
#define LK1 (KRG+2304)
#define LV1 (KRG+5760)
#define LO0q (KRG)            // O0: 1152
#define LO1q (KRG+1152)       // O1: 3456
#define FR0q (KRG+4608)       // res f0: 1024
#define FR1q (KRG+5632)       // res f1: 3072
#define LDSU 13312    // 53,248 B -> 3 blocks/CU

__global__ __launch_bounds__(256, 3) void k_layer(const u32* __restrict__ W16, int l,
    const u32* __restrict__ f0i, const u32* __restrict__ f1i,
    const int* __restrict__ nbr, const u16* __restrict__ rhat,
    u32* __restrict__ f0o, u32* __restrict__ f1o,
    const float* __restrict__ wout, const float* __restrict__ bout,
    float* __restrict__ out,
    const float* __restrict__ x, const float* __restrict__ win1,
    const float* __restrict__ te2) {
  __shared__ __align__(16) u32 S[LDSU];
  int tid = threadIdx.x, wv = tid >> 6, lane = tid & 63;
  int arow = lane & 15, aq = lane >> 4;
  int t0g = blockIdx.x * 32;
  int b = t0g >> 13, n0 = t0g & (NN-1);
  const u32 ONE2 = 0x3C003C00u;

  // ---- P0: residual into regs (l==0: computed; else pre-issued loads) ----
  uint4 res0, res1a, res1b, res1c;
  if (l == 0) {
    {
      int t0 = tid >> 3, j0 = (tid & 7)*4;
      const float* x3 = x + ((size_t)b*NN + n0 + t0)*3;
      float xv[3] = {x3[0], x3[1], x3[2]};
      u32 tmp[4];
#pragma unroll
      for (int q = 0; q < 4; ++q) {
        int ca = 2*(j0+q), cb = ca+1;
        float va = (ca < TC) ? te2[b*TC+ca] : xv[ca-61];
        float vb = (cb < TC) ? te2[b*TC+cb] : xv[cb-61];
        tmp[q] = packf16(va, vb);
      }
      res0 = make_uint4(tmp[0], tmp[1], tmp[2], tmp[3]);
    }
    uint4* rr[3] = {&res1a, &res1b, &res1c};
#pragma unroll
    for (int k = 0; k < 3; ++k) {
      int idx = k*1024 + tid*4;
      int t = idx/96, rem = idx%96, v = rem >> 5, j = rem & 31;
      float xv = x[((size_t)b*NN + n0 + t)*3 + v];
      u32 tmp[4];
#pragma unroll
      for (int q = 0; q < 4; ++q)
        tmp[q] = packf16(xv*win1[2*(j+q)], xv*win1[2*(j+q)+1]);
      *rr[k] = make_uint4(tmp[0], tmp[1], tmp[2], tmp[3]);
    }
  } else {
    const u32* s0 = f0i + ((size_t)b*NN + n0)*32;   // 1024 u32 contiguous
    const u32* s1 = f1i + ((size_t)b*NN + n0)*96;   // 3072 u32 contiguous
    res0  = *(const uint4*)(s0 + tid*4);
    res1a = *(const uint4*)(s1 + (0*256 + tid)*4);
    res1b = *(const uint4*)(s1 + (1*256 + tid)*4);
    res1c = *(const uint4*)(s1 + (2*256 + tid)*4);
  }

  // ---- P2: norms in A-frag regs (fdot2/pk) + QKV projections ----
  {
    const u32* base = W16 + 139264 + l*12288;
    int ncol = arow, mb = aq*4;

    auto ldraw = [&](int hr0, u32* r0, u32 (*r1)[8]) {
      int n = n0 - 2 + hr0 + arow;
      n = n < 0 ? 0 : (n > NN-1 ? NN-1 : n);
      size_t gt = (size_t)b*NN + n;
      if (l == 0) {
        const float* x3 = x + gt*3;
        float xv[3] = {x3[0], x3[1], x3[2]};
#pragma unroll
        for (int i = 0; i < 8; ++i) {
          int j = (i < 4) ? (aq*4+i) : (16 + aq*4 + (i-4));
          int ca = 2*j, cb = ca+1;
          float va = (ca < TC) ? te2[b*TC+ca] : xv[ca-61];
          float vb = (cb < TC) ? te2[b*TC+cb] : xv[cb-61];
          r0[i] = packf16(va, vb);
          float wa = win1[ca], wb = win1[cb];
#pragma unroll
          for (int v = 0; v < 3; ++v)
            r1[v][i] = packf16(xv[v]*wa, xv[v]*wb);
        }
      } else {
        *(uint4*)(r0)   = *(const uint4*)(f0i + gt*32 + aq*4);
        *(uint4*)(r0+4) = *(const uint4*)(f0i + gt*32 + 16 + aq*4);
#pragma unroll
        for (int v = 0; v < 3; ++v) {
          *(uint4*)(r1[v])   = *(const uint4*)(f1i + (gt*3+v)*32 + aq*4);
          *(uint4*)(r1[v]+4) = *(const uint4*)(f1i + (gt*3+v)*32 + 16 + aq*4);
        }
      }
    };

    auto mknorm = [&](const u32* r0, const u32 (*r1)[8], h8* g0f, h8 (*g1f)[2]) {
      float s = 0.f, s2 = 0.f;
#pragma unroll
      for (int i = 0; i < 8; ++i) { s = fdot2(r0[i], ONE2, s); s2 = fdot2(r0[i], r0[i], s2); }
      s  += __shfl_xor(s, 16, 64);  s  += __shfl_xor(s, 32, 64);
      s2 += __shfl_xor(s2, 16, 64); s2 += __shfl_xor(s2, 32, 64);
      float mu = s*(1.f/64.f);
      float ri = frsq(fmaxf(s2*(1.f/64.f)-mu*mu, 0.f) + EPSF);
      _Float16 rih = (_Float16)ri, bih = (_Float16)(-mu*ri);
      h2f scv; scv.x = rih; scv.y = rih;
      h2f biv; biv.x = bih; biv.y = bih;
#pragma unroll
      for (int kc = 0; kc < 2; ++kc) {
        u32 t0[4];
#pragma unroll
        for (int i = 0; i < 4; ++i) {
          h2f g = __builtin_bit_cast(h2f, r0[kc*4+i]) * scv + biv;
          t0[i] = __builtin_bit_cast(u32, g);
        }
        g0f[kc] = __builtin_bit_cast(h8, make_uint4(t0[0], t0[1], t0[2], t0[3]));
      }
      float ss = 0.f;
#pragma unroll
      for (int v = 0; v < 3; ++v)
#pragma unroll
        for (int i = 0; i < 8; ++i) ss = fdot2(r1[v][i], r1[v][i], ss);
      ss += __shfl_xor(ss, 16, 64); ss += __shfl_xor(ss, 32, 64);
      float vs = frsq(ss*(1.f/64.f) + EPSF);
      _Float16 vsh = (_Float16)vs;
      h2f vsv; vsv.x = vsh; vsv.y = vsh;
#pragma unroll
      for (int v = 0; v < 3; ++v)
#pragma unroll
        for (int kc = 0; kc < 2; ++kc) {
          u32 t1[4];
#pragma unroll
          for (int i = 0; i < 4; ++i) {
            h2f g = __builtin_bit_cast(h2f, r1[v][kc*4+i]) * vsv;
            t1[i] = __builtin_bit_cast(u32, g);
          }
          g1f[v][kc] = __builtin_bit_cast(h8, make_uint4(t1[0], t1[1], t1[2], t1[3]));
        }
    };

    auto projs = [&](const h8* afr, const u32* wM, u16* outh, int ob, int rmax) {
#pragma unroll
      for (int nt = 0; nt < 4; ++nt) {
        f4 acc = {0.f, 0.f, 0.f, 0.f};
#pragma unroll
        for (int kc = 0; kc < 2; ++kc) {
          uint4 wb = *(const uint4*)(wM + (nt*2+kc)*256 + lane*4);
          acc = __builtin_amdgcn_mfma_f32_16x16x32_f16(afr[kc], __builtin_bit_cast(h8, wb), acc, 0, 0, 0);
        }
        int ex = ((nt ^ aq)&3)*16 + ncol;   // aq-XOR swizzle
#pragma unroll
        for (int r = 0; r < 4; ++r) {
          int orow = ob + mb + r;
          if (orow < rmax) outh[orow*64 + ex] = f16b(acc[r]);
        }
      }
    };

    h8 g0f[2]; h8 g1f[3][2];
    if (wv < 3) {
      int tb = wv*16;
      u32 r0[8]; u32 r1[3][8];
      ldraw(tb, r0, r1);
      mknorm(r0, r1, g0f, g1f);
      projs(g0f, base + 1*2048, (u16*)(S+LK0), tb, 36);
      projs(g0f, base + 2*2048, (u16*)(S+LV0), tb, 36);
#pragma unroll
      for (int v = 0; v < 3; ++v) {
        projs(g1f[v], base + 4*2048, (u16*)(S+LK1) + v*2304, tb, 36);
        projs(g1f[v], base + 5*2048, (u16*)(S+LV1) + v*2304, tb, 36);
      }
    } else {
      u32 r0a[8], r1a[3][8], r0b[8], r1b[3][8];
      ldraw(2, r0a, r1a);        // both tiles' loads issue before any compute
      ldraw(18, r0b, r1b);
      mknorm(r0a, r1a, g0f, g1f);
      projs(g0f, base, (u16*)(S+QH), 0, 32);
#pragma unroll
      for (int v = 0; v < 3; ++v)
        projs(g1f[v], base + 3*2048, (u16*)(S+1024) + v*2048, 0, 32);
      mknorm(r0b, r1b, g0f, g1f);
      projs(g0f, base, (u16*)(S+QH), 16, 32);
#pragma unroll
      for (int v = 0; v < 3; ++v)
        projs(g1f[v], base + 3*2048, (u16*)(S+1024) + v*2048, 16, 32);
    }
  }
  __syncthreads();   // BAR 1: Q/K/V staged

  // ---- P3: attention, packed f16 end-to-end: 2 ch/lane, 2 tokens/iter ----
  u32 O0k[4], O1k[4][3];
  {
    const u32* Q0u = S + QH;
    const u32* Q1u = S + 1024;
    const u32* K0u = S + LK0;
    const u32* V0u = S + LV0;
    const u32* K1u = S + LK1;
    const u32* V1u = S + LV1;
    int half = lane >> 5, l32 = lane & 31;
#pragma unroll
    for (int it = 0; it < 4; ++it) {
      int ct = wv*8 + it*2 + half;
      int n = n0 + ct;
      size_t gt = (size_t)b*NN + n;
      int km = kmax_of(n);
      int4 nb = *(const int4*)(nbr + n*4);
      int lr[4];
      {
        int xx;
        xx = nb.x - n0 + 2; lr[0] = xx < 0 ? 0 : (xx > 35 ? 35 : xx);
        xx = nb.y - n0 + 2; lr[1] = xx < 0 ? 0 : (xx > 35 ? 35 : xx);
        xx = nb.z - n0 + 2; lr[2] = xx < 0 ? 0 : (xx > 35 ? 35 : xx);
        xx = nb.w - n0 + 2; lr[3] = xx < 0 ? 0 : (xx > 35 ? 35 : xx);
      }
      int jq = l32 ^ (((ct>>2)&3)<<3);
      u32 q0p = Q0u[ct*32 + jq];
      u32 q1p[3];
#pragma unroll
      for (int v = 0; v < 3; ++v) q1p[v] = Q1u[v*1024 + ct*32 + jq];
      float p[4];
#pragma unroll
      for (int k = 0; k < 4; ++k) {
        int row = lr[k];
        int jk = l32 ^ (((row>>2)&3)<<3);
        float acc = fdot2(q0p, K0u[row*32 + jk], 0.f);
#pragma unroll
        for (int v = 0; v < 3; ++v)
          acc = fdot2(q1p[v], K1u[v*1152 + row*32 + jk], acc);
        p[k] = acc;
      }
#pragma unroll
      for (int m = 1; m < 8; m <<= 1) {
#pragma unroll
        for (int k = 0; k < 4; ++k) p[k] += __shfl_xor(p[k], m, 64);
      }
      float mx = -1e30f;
#pragma unroll
      for (int k = 0; k < 4; ++k) { p[k] *= 0.25f; if (k < km) mx = fmaxf(mx, p[k]); }
      float aw[4], ssum = 0.f;
#pragma unroll
      for (int k = 0; k < 4; ++k) { aw[k] = (k < km) ? fexp(p[k]-mx) : 0.f; ssum += aw[k]; }
      float inv = frcp(ssum);
      const uint2* rp = (const uint2*)(rhat + (size_t)gt*12);
      uint2 ra = rp[0], rb = rp[1], rc = rp[2];
      u32 rw[6] = {ra.x, ra.y, rb.x, rb.y, rc.x, rc.y};
      h2f o0p = {(_Float16)0.f, (_Float16)0.f};
      h2f o1p0 = o0p, o1p1 = o0p, o1p2 = o0p;
#pragma unroll
      for (int k = 0; k < 4; ++k) {
        int row = lr[k];
        int jk = l32 ^ (((row>>2)&3)<<3);
        float a = aw[k]*inv;
        _Float16 ah = (_Float16)a;
        h2f a2; a2.x = ah; a2.y = ah;
        h2f v0p = __builtin_bit_cast(h2f, V0u[row*32 + jk]);
        h2f v1p[3], rh2[3];
#pragma unroll
        for (int v = 0; v < 3; ++v) {
          v1p[v] = __builtin_bit_cast(h2f, V1u[v*1152 + row*32 + jk]);
          int idx = k*3 + v;
          u32 w = rw[idx>>1];
          u32 hh = (idx&1) ? (w >> 16) : (w & 0xffffu);
          rh2[v] = __builtin_bit_cast(h2f, (hh << 16) | hh);
        }
        h2f vd = v1p[0]*rh2[0];
        vd = v1p[1]*rh2[1] + vd;
        vd = v1p[2]*rh2[2] + vd;
        o0p  = a2*(v0p + vd) + o0p;
        o1p0 = a2*(v0p*rh2[0] + v1p[0]) + o1p0;
        o1p1 = a2*(v0p*rh2[1] + v1p[1]) + o1p1;
        o1p2 = a2*(v0p*rh2[2] + v1p[2]) + o1p2;
      }
      O0k[it] = __builtin_bit_cast(u32, o0p);
      O1k[it][0] = __builtin_bit_cast(u32, o1p0);
      O1k[it][1] = __builtin_bit_cast(u32, o1p1);
      O1k[it][2] = __builtin_bit_cast(u32, o1p2);
    }
  }
  __syncthreads();   // BAR 2: K/V reads done -> region dead

  // ---- merged write phase: O + residuals into K-region ----
  {
    u32* o0u = S + LO0q;
    u32* o1u = S + LO1q;
    int half = lane >> 5, l32 = lane & 31;
#pragma unroll
    for (int it = 0; it < 4; ++it) {
      int ct = wv*8 + it*2 + half;
      o0u[ct*36 + l32] = O0k[it];
#pragma unroll
      for (int v = 0; v < 3; ++v)
        o1u[(v*32+ct)*36 + l32] = O1k[it][v];
    }
    uint4* d0 = (uint4*)(S + FR0q);
    d0[tid] = res0;
    uint4* d1 = (uint4*)(S + FR1q);
    d1[tid]       = res1a;
    d1[256 + tid] = res1b;
    d1[512 + tid] = res1c;
  }
  __syncthreads();   // BAR 3: O + residuals visible

  // ---- P4: out-proj + FF (waves 0-1: f1 path; waves 2-3: f0 path) ----
  {
    int tl16 = (wv & 1)*16;
    int ncol = arow, mb = aq*4;
    const u32* Wf = W16 + 188416 + l*22528;
    const u32* po0f = Wf;
    const u32* po1f = Wf + 2048;
    const u32* pf1f = Wf + 4096;
    const u32* paf  = Wf + 6144;
    const u32* pbf  = Wf + 14336;
    const u32* FR0 = S + FR0q;
    const u32* FR1 = S + FR1q;
    size_t gt0 = (size_t)b*NN + n0 + tl16;
    if (wv < 2) {
      // f1 path: Wo1 + residual -> vnorm -> ff1 + residual -> f1o (or score at l==3)
      h8 a1[3][2];
#pragma unroll
      for (int v = 0; v < 3; ++v)
#pragma unroll
        for (int kc = 0; kc < 2; ++kc)
          a1[v][kc] = __builtin_bit_cast(h8, *(const uint4*)(S + LO1q + (v*32 + tl16 + arow)*36 + kc*16 + aq*4));
      float f1m[3][4][4];
#pragma unroll
      for (int v = 0; v < 3; ++v)
#pragma unroll
        for (int nt = 0; nt < 4; ++nt) {
          f4 acc = {0.f, 0.f, 0.f, 0.f};
#pragma unroll
          for (int kc = 0; kc < 2; ++kc) {
            uint4 wb = *(const uint4*)(po1f + (nt*2+kc)*256 + lane*4);
            acc = __builtin_amdgcn_mfma_f32_16x16x32_f16(a1[v][kc], __builtin_bit_cast(h8, wb), acc, 0, 0, 0);
          }
#pragma unroll
          for (int r = 0; r < 4; ++r) {
            int t = tl16 + mb + r;
            float2 pq = unpk(FR1[(t*3+v)*32 + nt*8 + (ncol>>1)]);
            f1m[v][nt][r] = acc[r] + ((ncol&1) ? pq.y : pq.x);
          }
        }
      float vs[4];
#pragma unroll
      for (int r = 0; r < 4; ++r) {
        float ss = 0.f;
#pragma unroll
        for (int v = 0; v < 3; ++v)
#pragma unroll
          for (int nt = 0; nt < 4; ++nt) ss += f1m[v][nt][r]*f1m[v][nt][r];
        ss += __shfl_xor(ss, 1, 64); ss += __shfl_xor(ss, 2, 64);
        ss += __shfl_xor(ss, 4, 64); ss += __shfl_xor(ss, 8, 64);
        vs[r] = frsq(ss*(1.f/64.f) + EPSF);
      }
      // vn overlays this wave's OWN FR1 region (residuals already consumed)
      u32* vn = S + FR1q + wv*1536;
      {
        u16* vnh = (u16*)vn;
#pragma unroll
        for (int v = 0; v < 3; ++v)
#pragma unroll
          for (int nt = 0; nt < 4; ++nt)
#pragma unroll
            for (int r = 0; r < 4; ++r)
              vnh[v*1024 + (mb+r)*64 + ((nt^aq)&3)*16 + ncol] = f16b(f1m[v][nt][r]*vs[r]);
      }
      float wl[3][4], sc[3][4];
      if (l == 3) {
#pragma unroll
        for (int v = 0; v < 3; ++v)
#pragma unroll
          for (int nt = 0; nt < 4; ++nt) { wl[v][nt] = wout[v*64 + nt*16 + ncol]; }
#pragma unroll
        for (int v = 0; v < 3; ++v)
#pragma unroll
          for (int r = 0; r < 4; ++r) sc[v][r] = 0.f;
      }
#pragma unroll
      for (int v = 0; v < 3; ++v)
#pragma unroll
        for (int nt = 0; nt < 4; ++nt) {
          f4 acc = {0.f, 0.f, 0.f, 0.f};
#pragma unroll
          for (int kc = 0; kc < 2; ++kc) {
            int lc = kc*2 + (aq>>1);
            int pc = (lc ^ (arow>>2)) & 3;
            h8 af = __builtin_bit_cast(h8, *(const uint4*)(vn + v*512 + arow*32 + pc*8 + (aq&1)*4));
            uint4 wb = *(const uint4*)(pf1f + (nt*2+kc)*256 + lane*4);
            acc = __builtin_amdgcn_mfma_f32_16x16x32_f16(af, __builtin_bit_cast(h8, wb), acc, 0, 0, 0);
          }
#pragma unroll
          for (int r = 0; r < 4; ++r) {
            size_t gt = gt0 + mb + r;
            float val = acc[r] + f1m[v][nt][r];
            if (l < 3) {
              float par = __shfl_xor(val, 1, 64);
              if (!(ncol & 1))
                f1o[(gt*3+v)*32 + nt*8 + (ncol>>1)] = packf16(val, par);
            } else {
              sc[v][r] += val * wl[v][nt];
            }
          }
        }
      if (l == 3) {
#pragma unroll
        for (int v = 0; v < 3; ++v)
#pragma unroll
          for (int r = 0; r < 4; ++r) {
            float xx = sc[v][r];
            xx += __shfl_xor(xx, 1, 64); xx += __shfl_xor(xx, 2, 64);
            xx += __shfl_xor(xx, 4, 64); xx += __shfl_xor(xx, 8, 64);
            if (ncol == 0) out[(gt0 + mb + r)*3 + v] = xx + bout[v];
          }
      }
    } else if (l < 3) {
      // f0 path: Wo0 + residual -> LN -> ffa/silu -> ffb + residual -> f0o
      h8 a0[2];
#pragma unroll
      for (int kc = 0; kc < 2; ++kc)
        a0[kc] = __builtin_bit_cast(h8, *(const uint4*)(S + LO0q + (tl16 + arow)*36 + kc*16 + aq*4));
      float f0m[4][4];
#pragma unroll
      for (int nt = 0; nt < 4; ++nt) {
        f4 acc = {0.f, 0.f, 0.f, 0.f};
#pragma unroll
        for (int kc = 0; kc < 2; ++kc) {
          uint4 wb = *(const uint4*)(po0f + (nt*2+kc)*256 + lane*4);
          acc = __builtin_amdgcn_mfma_f32_16x16x32_f16(a0[kc], __builtin_bit_cast(h8, wb), acc, 0, 0, 0);
        }
#pragma unroll
        for (int r = 0; r < 4; ++r) {
          int t = tl16 + mb + r;
          float2 pq = unpk(FR0[t*32 + nt*8 + (ncol>>1)]);
          f0m[nt][r] = acc[r] + ((ncol&1) ? pq.y : pq.x);
        }
      }
      float mu[4], ri[4];
#pragma unroll
      for (int r = 0; r < 4; ++r) {
        float sg = 0.f, s2 = 0.f;
#pragma unroll
        for (int nt = 0; nt < 4; ++nt) { sg += f0m[nt][r]; s2 += f0m[nt][r]*f0m[nt][r]; }
        sg += __shfl_xor(sg, 1, 64); sg += __shfl_xor(sg, 2, 64);
        sg += __shfl_xor(sg, 4, 64); sg += __shfl_xor(sg, 8, 64);
        s2 += __shfl_xor(s2, 1, 64); s2 += __shfl_xor(s2, 2, 64);
        s2 += __shfl_xor(s2, 4, 64); s2 += __shfl_xor(s2, 8, 64);
        mu[r] = sg*(1.f/64.f);
        ri[r] = frsq(fmaxf(s2*(1.f/64.f)-mu[r]*mu[r], 0.f) + EPSF);
      }
      // gg overlays this wave's OWN FR0 region
      u32* gg = S + FR0q + (wv & 1)*512;
      {
        u16* gh = (u16*)gg;
#pragma unroll
        for (int nt = 0; nt < 4; ++nt)
#pragma unroll
          for (int r = 0; r < 4; ++r)
            gh[(mb+r)*64 + ((nt^aq)&3)*16 + ncol] = f16b((f0m[nt][r]-mu[r])*ri[r]);
      }
      // hp: 16 rows x 256 halves (128 u32), chunk-XOR swizzled; fits 2x2048 in Q region
      u32* hp = S + (wv-2)*2048;
      {
        h8 ga[2];
#pragma unroll
        for (int kc = 0; kc < 2; ++kc) {
          int lc = kc*2 + (aq>>1);
          int pc = (lc ^ (arow>>2)) & 3;
          ga[kc] = __builtin_bit_cast(h8, *(const uint4*)(gg + arow*32 + pc*8 + (aq&1)*4));
        }
        u16* hhh = (u16*)hp;
#pragma unroll
        for (int nt16 = 0; nt16 < 16; ++nt16) {
          f4 acc = {0.f, 0.f, 0.f, 0.f};
#pragma unroll
          for (int kc = 0; kc < 2; ++kc) {
            uint4 wb = *(const uint4*)(paf + (nt16*2+kc)*256 + lane*4);
            acc = __builtin_amdgcn_mfma_f32_16x16x32_f16(ga[kc], __builtin_bit_cast(h8, wb), acc, 0, 0, 0);
          }
#pragma unroll
          for (int r = 0; r < 4; ++r) {
            float a = acc[r];
            int row = mb + r;
            int chunk = (nt16*2 + (ncol>>3)) ^ (row & 7);
            hhh[row*256 + chunk*8 + (ncol&7)] = f16b(a * frcp(1.f + fexp(-a)));
          }
        }
      }
#pragma unroll
      for (int nt = 0; nt < 4; ++nt) {
        f4 acc = {0.f, 0.f, 0.f, 0.f};
#pragma unroll
        for (int kc = 0; kc < 8; ++kc) {
          int c = kc*4 + aq;
          h8 af = __builtin_bit_cast(h8, *(const uint4*)(hp + arow*128 + ((c ^ (arow & 7))<<2)));
          uint4 wb = *(const uint4*)(pbf + (nt*8+kc)*256 + lane*4);
          acc = __builtin_amdgcn_mfma_f32_16x16x32_f16(af, __builtin_bit_cast(h8, wb), acc, 0, 0, 0);
        }
#pragma unroll
        for (int r = 0; r < 4; ++r) {
          size_t gt = gt0 + mb + r;
          float val = acc[r] + f0m[nt][r];
          float par = __shfl_xor(val, 1, 64);
          if (!(ncol & 1))
            f0o[gt*32 + nt*8 + (ncol>>1)] = packf16(val, par);
        }
      }
    }
  }
}

extern "C" void kernel_launch(void* const* d_in, const int* in_sizes, int n_in,
                              void* d_out, int out_size, void* d_ws, size_t ws_size,
                              hipStream_t stream) {
  float* out = (float*)d_out;
  static const int exp23[23] = {196608,196608,8,32768,32768,16384,128,7808,61,64,
                                16384,16384,16384,16384,16384,16384,16384,16384,
                                65536,65536,16384,192,3};
  bool ok23 = (n_in == 23), ok22 = (n_in == 22);
  int bad = -1;
  if (ok23) {
    for (int i = 0; i < 23; ++i) if (in_sizes[i] != exp23[i]) { ok23 = false; bad = i; break; }
  }
  if (!ok23 && ok22) {
    for (int i = 0; i < 22; ++i) {
      int want = (i == 0) ? exp23[0] : exp23[i+1];
      if (in_sizes[i] != want) { ok22 = false; if (bad < 0) bad = i; break; }
    }
  } else ok22 = false;
  if (!ok23 && !ok22) {
    k_const<<<768, 256, 0, stream>>>(out, (float)(3000 + (bad < 0 ? 100 + n_in : bad)));
    return;
  }
  int sh = ok23 ? 0 : -1;
  const int* nbr = (const int*)d_in[3 + sh];
  const float* F[20];
  F[0] = (const float*)d_in[0];
  F[1] = (const float*)d_in[2 + sh];
  for (int j = 0; j < 18; ++j) F[2 + j] = (const float*)d_in[5 + sh + j];

  char* ws = (char*)d_ws;
  u32*   W16  = (u32*)ws;                           // 1,114,112 B
  float* te2  = (float*)(ws + 1114112);             // 2,048 B
  u16*   rhat = (u16*)(ws + 1116160);               // 1,572,864 B
  u32*   f0A  = (u32*)(ws + 2689024);               // 8,388,608 B
  u32*   f1A  = (u32*)(ws + 11077632);              // 25,165,824 B
  u32*   f0B  = (u32*)(ws + 36243456);              // 8,388,608 B
  u32*   f1B  = (u32*)(ws + 44632064);              // 25,165,824 B -> end 69,797,888

  WSrc s;
  s.m[0]=F[7]; s.m[1]=F[8]; s.m[2]=F[9]; s.m[3]=F[10]; s.m[4]=F[11]; s.m[5]=F[12];
  s.m[6]=F[13]; s.m[7]=F[14]; s.m[8]=F[17]; s.m[9]=F[15]; s.m[10]=F[16];

  k_prep<<<1096 + BN*4/256, 256, 0, stream>>>(s, W16, F[1], F[2], F[3], F[4], F[5], te2,
                                              F[0], nbr, rhat);
  for (int l = 0; l < LL; ++l) {
    const u32* fi0 = (l & 1) ? f0B : f0A;
    const u32* fi1 = (l & 1) ? f1B : f1A;
    u32*       fo0 = (l & 1) ? f0A : f0B;
    u32*       fo1 = (l & 1) ? f1A : f1B;
    k_layer<<<BN/32, 256, 0, stream>>>(W16, l, fi0, fi1, nbr, rhat, fo0, fo1,
                                       F[18], F[19], out, F[0], F[6], te2);
  }
}